// Round 18
// baseline (522.346 us; speedup 1.0000x reference)
//
#include <hip/hip_runtime.h>
#include <hip/hip_bf16.h>

typedef __hip_bfloat16 bf16;
typedef short short8 __attribute__((ext_vector_type(8)));
typedef float f32x4 __attribute__((ext_vector_type(4)));

__device__ __forceinline__ float b2f(bf16 v){ return __bfloat162float(v); }

__device__ __forceinline__ short f2bs(float f){
  union { __hip_bfloat16 b; short s; } u; u.b = __float2bfloat16(f); return u.s;
}
__device__ __forceinline__ float bs2f(short s){
  union { short s; __hip_bfloat16 b; } u; u.s = s; return __bfloat162float(u.b);
}

__device__ __forceinline__ float wred_sum(float v){
  #pragma unroll
  for (int o = 32; o > 0; o >>= 1) v += __shfl_xor(v, o, 64);
  return v;
}

// ---------------------------------------------------------------------------
// modality helper (128 threads)
// ---------------------------------------------------------------------------
template<int DIMN>
__device__ void modality(const float* x, const float* W, const float* bia, const float* ph,
                         float* PURE, float* RNORM, int m, int bt, float* xs, float* red)
{
  int tid = threadIdx.x;
  for (int i = tid; i < DIMN; i += 128) xs[i] = x[bt*DIMN + i];
  __syncthreads();
  float a0 = 0.f, a1 = 0.f, a2 = 0.f, a3 = 0.f;
  int k = 0;
  for (; k + 4 <= DIMN; k += 4){
    a0 = fmaf(xs[k],   W[(k  )*128 + tid], a0);
    a1 = fmaf(xs[k+1], W[(k+1)*128 + tid], a1);
    a2 = fmaf(xs[k+2], W[(k+2)*128 + tid], a2);
    a3 = fmaf(xs[k+3], W[(k+3)*128 + tid], a3);
  }
  for (; k < DIMN; k++) a0 = fmaf(xs[k], W[k*128 + tid], a0);
  float acc = bia[tid] + ((a0 + a1) + (a2 + a3));
  float rep = fmaxf(acc, 0.f);
  float s = wred_sum(rep*rep);
  int wid = tid >> 6, lane = tid & 63;
  if (lane == 0) red[wid] = s;
  __syncthreads();
  float nrm = sqrtf(red[0] + red[1]);
  float amp = rep / fmaxf(nrm, 1e-12f);
  float p = ph[tid];
  PURE[bt*768 + m*128 + tid]       = amp * cosf(p);
  PURE[bt*768 + (3+m)*128 + tid]   = amp * sinf(p);
  if (tid == 0) RNORM[bt*4 + m] = nrm;
}

// ---------------------------------------------------------------------------
// Kernel 0 MERGED PREP: wT (blocks 0..383) + proj (384..1151) + lang (1152).
// block 128 threads.
// ---------------------------------------------------------------------------
__global__ void prep_kernel(
    const float* __restrict__ Wqkv, const float* __restrict__ Wo,
    const float* __restrict__ W1, const float* __restrict__ W2,
    short* __restrict__ WqkvT, short* __restrict__ WoT,
    short* __restrict__ W1T, short* __restrict__ W2T,
    const float* xt, const float* xv, const float* xa,
    const float* Wpt, const float* bpt, const float* Wpv, const float* bpv,
    const float* Wpa, const float* bpa,
    const float* pht, const float* phv, const float* pha,
    float* PURE, float* RNORM,
    const float* l1, const float* l2,
    const float* Wl1, const float* bl1, const float* Wl2, const float* bl2,
    float* LANGB)
{
  __shared__ float xs[600];
  __shared__ float xs2a[300];
  __shared__ float red[4];
  int b = blockIdx.x, tid = threadIdx.x;

  if (b < 384){
    int l = b / 192, bb = b - l*192;
    const float* in; short* out; int K, N, boff;
    if (bb < 48)      { in = Wqkv; out = WqkvT; K = 128; N = 384; boff = bb; }
    else if (bb < 64) { in = Wo;   out = WoT;   K = 128; N = 128; boff = bb - 48; }
    else if (bb < 128){ in = W1;   out = W1T;   K = 128; N = 512; boff = bb - 64; }
    else              { in = W2;   out = W2T;   K = 512; N = 128; boff = bb - 128; }
    int base = l * K * N;
    int i0 = boff * 1024;
    #pragma unroll
    for (int t = 0; t < 8; t++){
      int i = i0 + t*128 + tid;
      if (i < K*N){
        int nn = i / K, kk = i - nn*K;
        out[base + i] = f2bs(in[base + kk*N + nn]);
      }
    }
    return;
  }
  if (b < 1152){
    int idx = b - 384;
    int bt = idx & 255, m = idx >> 8;
    if (m == 0)      modality<600>(xt, Wpt, bpt, pht, PURE, RNORM, 0, bt, xs, red);
    else if (m == 1) modality<342>(xv, Wpv, bpv, phv, PURE, RNORM, 1, bt, xs, red);
    else             modality<300>(xa, Wpa, bpa, pha, PURE, RNORM, 2, bt, xs, red);
    return;
  }
  // ---- lang path (single block) ----
  for (int i = tid; i < 300; i += 128){ xs[i] = l1[i]; xs2a[i] = l2[i]; }
  __syncthreads();
  float p10=0,p11=0,p12=0,p13=0, p20=0,p21=0,p22=0,p23=0;
  for (int k = 0; k < 300; k += 4){
    p10 = fmaf(xs[k],    Wl1[(k  )*128+tid], p10);
    p11 = fmaf(xs[k+1],  Wl1[(k+1)*128+tid], p11);
    p12 = fmaf(xs[k+2],  Wl1[(k+2)*128+tid], p12);
    p13 = fmaf(xs[k+3],  Wl1[(k+3)*128+tid], p13);
    p20 = fmaf(xs2a[k],  Wl2[(k  )*128+tid], p20);
    p21 = fmaf(xs2a[k+1],Wl2[(k+1)*128+tid], p21);
    p22 = fmaf(xs2a[k+2],Wl2[(k+2)*128+tid], p22);
    p23 = fmaf(xs2a[k+3],Wl2[(k+3)*128+tid], p23);
  }
  float a1 = bl1[tid] + ((p10+p11)+(p12+p13));
  float a2 = bl2[tid] + ((p20+p21)+(p22+p23));
  a1 = fmaxf(a1, 0.f); a2 = fmaxf(a2, 0.f);
  int wid = tid >> 6, lane = tid & 63;
  float s1 = wred_sum(a1*a1), s2 = wred_sum(a2*a2);
  if (lane == 0){ red[wid] = s1; red[2+wid] = s2; }
  __syncthreads();
  float n1 = sqrtf(red[0] + red[1]);
  float n2 = sqrtf(red[2] + red[3]);
  float lamp1 = a1 / fmaxf(n1, 1e-12f);
  float lamp2 = a2 / fmaxf(n2, 1e-12f);
  float ph = pht[tid];
  float c = cosf(ph), s = sinf(ph);
  const float s2c = 0.70710678118654752f;
  float h1r = (lamp1*c + lamp1*s)*s2c, h1i = (lamp1*c - lamp1*s)*s2c;
  float h2r = (lamp2*c + lamp2*s)*s2c, h2i = (lamp2*c - lamp2*s)*s2c;
  float er = h1r*h2r - h1i*h2i;
  float ei = h1r*h2i + h1i*h2r;
  __syncthreads();
  float se = wred_sum(er*er + ei*ei);
  if (lane == 0) red[wid] = se;
  __syncthreads();
  float en = fmaxf(sqrtf(red[0] + red[1]), 1e-12f);
  LANGB[tid]       = er / en;
  LANGB[128 + tid] = ei / en;
  if (tid == 0) LANGB[256] = n1;
}

// ---------------------------------------------------------------------------
// Kernel 3: weighted sum of rank-1 density matrices -> Xb (bf16). grid 512.
// ---------------------------------------------------------------------------
__global__ __launch_bounds__(256) void rho_kernel(const float* PURE, const float* RNORM,
                                                  const float* LANGB, short* Xb)
{
  __shared__ float rv[4][128], iv[4][128], wsm[4];
  int bt = blockIdx.x >> 1, half = blockIdx.x & 1;
  int tid = threadIdx.x;
  for (int i = tid; i < 1024; i += 256){
    int d = i & 127;
    if (i < 768){ int m = i >> 7; float v = PURE[bt*768 + i];
                  if (m < 3) rv[m][d] = v; else iv[m-3][d] = v; }
    else if (i < 896) rv[3][d] = LANGB[d];
    else              iv[3][d] = LANGB[128 + d];
  }
  if (tid == 0){
    float n0 = RNORM[bt*4+0], n1 = RNORM[bt*4+1], n2 = RNORM[bt*4+2], n3 = LANGB[256];
    float mx = fmaxf(fmaxf(n0, n1), fmaxf(n2, n3));
    float e0 = __expf(n0-mx), e1 = __expf(n1-mx), e2 = __expf(n2-mx), e3 = __expf(n3-mx);
    float inv = 1.f / (e0+e1+e2+e3);
    wsm[0]=e0*inv; wsm[1]=e1*inv; wsm[2]=e2*inv; wsm[3]=e3*inv;
  }
  __syncthreads();
  float w0 = wsm[0], w1 = wsm[1], w2 = wsm[2], w3 = wsm[3];
  int lo = half*8192, hi = lo + 8192;
  for (int idx = lo + tid; idx < hi; idx += 256){
    int d = idx >> 7, e = idx & 127;
    float rr = 0.f, ri = 0.f;
    {
      float rd=rv[0][d], re=rv[0][e], id=iv[0][d], ie=iv[0][e];
      rr = fmaf(w0, rd*re + id*ie, rr); ri = fmaf(w0, id*re - rd*ie, ri);
    }{
      float rd=rv[1][d], re=rv[1][e], id=iv[1][d], ie=iv[1][e];
      rr = fmaf(w1, rd*re + id*ie, rr); ri = fmaf(w1, id*re - rd*ie, ri);
    }{
      float rd=rv[2][d], re=rv[2][e], id=iv[2][d], ie=iv[2][e];
      rr = fmaf(w2, rd*re + id*ie, rr); ri = fmaf(w2, id*re - rd*ie, ri);
    }{
      float rd=rv[3][d], re=rv[3][e], id=iv[3][d], ie=iv[3][e];
      rr = fmaf(w3, rd*re + id*ie, rr); ri = fmaf(w3, id*re - rd*ie, ri);
    }
    Xb[(size_t)bt*16384 + idx]        = f2bs(rr);
    Xb[(size_t)(256+bt)*16384 + idx]  = f2bs(ri);
  }
}

// ---------------------------------------------------------------------------
// Kernel 4a: fused MHA per (sequence n, head h) via MFMA. grid (512,4), block 256.
// (round-12 version, measured best)
// ---------------------------------------------------------------------------
__global__ __launch_bounds__(256) void attn_kernel(const short* __restrict__ Xb,
    const short* __restrict__ WqkvT, const float* __restrict__ bqkv,
    bf16* __restrict__ ATTO)
{
  __shared__ __align__(16) char lds_raw[43520];
  short* Vt = (short*)(lds_raw);           // [32][136]
  short* Qs = (short*)(lds_raw + 8704);    // [128][40]
  short* Ks = (short*)(lds_raw + 18944);   // [128][40]
  short* Ps = (short*)(lds_raw + 8704);    // [128][136] overlays Qs/Ks

  const int n = blockIdx.x, h = blockIdx.y;
  const int tid = threadIdx.x;
  const int wid = tid >> 6, lane = tid & 63;
  const int l15 = lane & 15, quad = lane >> 4;
  const short* xn = Xb + (size_t)n*16384;

  f32x4 acc[2][6];
  #pragma unroll
  for (int mi = 0; mi < 2; mi++)
    #pragma unroll
    for (int nt = 0; nt < 6; nt++){
      f32x4 z = {0.f, 0.f, 0.f, 0.f}; acc[mi][nt] = z;
    }

  #pragma unroll
  for (int ks = 0; ks < 4; ks++){
    short8 afr[2];
    #pragma unroll
    for (int mi = 0; mi < 2; mi++){
      int row = (wid*2 + mi)*16 + l15;
      afr[mi] = *(const short8*)(xn + row*128 + ks*32 + quad*8);
    }
    #pragma unroll
    for (int nt = 0; nt < 6; nt++){
      int col = (nt >> 1)*128 + h*32 + (nt & 1)*16 + l15;
      short8 bfr = *(const short8*)(WqkvT + (size_t)col*128 + ks*32 + quad*8);
      #pragma unroll
      for (int mi = 0; mi < 2; mi++)
        acc[mi][nt] = __builtin_amdgcn_mfma_f32_16x16x32_bf16(afr[mi], bfr, acc[mi][nt], 0, 0, 0);
    }
  }
  #pragma unroll
  for (int nt = 0; nt < 6; nt++){
    int sec = nt >> 1;
    int cl = (nt & 1)*16 + l15;
    float bias = bqkv[sec*128 + h*32 + cl];
    #pragma unroll
    for (int mi = 0; mi < 2; mi++){
      int rowb = (wid*2 + mi)*16 + quad*4;
      #pragma unroll
      for (int r = 0; r < 4; r++){
        float v = acc[mi][nt][r] + bias;
        int row = rowb + r;
        if (sec == 0)      Qs[row*40 + cl] = f2bs(v * 0.17677669529663687f);
        else if (sec == 1) Ks[row*40 + cl] = f2bs(v);
        else               Vt[cl*136 + row] = f2bs(v);
      }
    }
  }
  __syncthreads();

  f32x4 s[2][8];
  {
    short8 qf[2];
    #pragma unroll
    for (int mi = 0; mi < 2; mi++){
      int row = (wid*2 + mi)*16 + l15;
      qf[mi] = *(const short8*)(Qs + row*40 + quad*8);
    }
    #pragma unroll
    for (int nt = 0; nt < 8; nt++){
      int kr = nt*16 + l15;
      short8 kf = *(const short8*)(Ks + kr*40 + quad*8);
      #pragma unroll
      for (int mi = 0; mi < 2; mi++){
        f32x4 z = {0.f, 0.f, 0.f, 0.f};
        s[mi][nt] = __builtin_amdgcn_mfma_f32_16x16x32_bf16(qf[mi], kf, z, 0, 0, 0);
      }
    }
  }

  #pragma unroll
  for (int mi = 0; mi < 2; mi++){
    #pragma unroll
    for (int r = 0; r < 4; r++){
      float m = -1e30f;
      #pragma unroll
      for (int nt = 0; nt < 8; nt++) m = fmaxf(m, s[mi][nt][r]);
      #pragma unroll
      for (int o = 1; o < 16; o <<= 1) m = fmaxf(m, __shfl_xor(m, o, 64));
      float sum = 0.f;
      #pragma unroll
      for (int nt = 0; nt < 8; nt++){
        float p = __expf(s[mi][nt][r] - m);
        s[mi][nt][r] = p; sum += p;
      }
      #pragma unroll
      for (int o = 1; o < 16; o <<= 1) sum += __shfl_xor(sum, o, 64);
      float inv = 1.f / sum;
      #pragma unroll
      for (int nt = 0; nt < 8; nt++) s[mi][nt][r] *= inv;
    }
  }
  __syncthreads();

  #pragma unroll
  for (int mi = 0; mi < 2; mi++){
    int rowb = (wid*2 + mi)*16 + quad*4;
    #pragma unroll
    for (int nt = 0; nt < 8; nt++){
      int col = nt*16 + l15;
      #pragma unroll
      for (int r = 0; r < 4; r++)
        Ps[(rowb + r)*136 + col] = f2bs(s[mi][nt][r]);
    }
  }
  __syncthreads();

  f32x4 o_[2][2];
  #pragma unroll
  for (int mi = 0; mi < 2; mi++)
    #pragma unroll
    for (int n2 = 0; n2 < 2; n2++){
      f32x4 z = {0.f, 0.f, 0.f, 0.f}; o_[mi][n2] = z;
    }
  #pragma unroll
  for (int ks = 0; ks < 4; ks++){
    short8 pf[2];
    #pragma unroll
    for (int mi = 0; mi < 2; mi++){
      int row = (wid*2 + mi)*16 + l15;
      pf[mi] = *(const short8*)(Ps + row*136 + ks*32 + quad*8);
    }
    #pragma unroll
    for (int n2 = 0; n2 < 2; n2++){
      short8 vf = *(const short8*)(Vt + (n2*16 + l15)*136 + ks*32 + quad*8);
      #pragma unroll
      for (int mi = 0; mi < 2; mi++)
        o_[mi][n2] = __builtin_amdgcn_mfma_f32_16x16x32_bf16(pf[mi], vf, o_[mi][n2], 0, 0, 0);
    }
  }
  bf16* on = ATTO + (size_t)n*16384;
  #pragma unroll
  for (int mi = 0; mi < 2; mi++){
    int rowb = (wid*2 + mi)*16 + quad*4;
    #pragma unroll
    for (int n2 = 0; n2 < 2; n2++){
      int col = h*32 + n2*16 + l15;
      #pragma unroll
      for (int r = 0; r < 4; r++)
        on[(rowb + r)*128 + col] = __float2bfloat16(o_[mi][n2][r]);
    }
  }
}

// ---------------------------------------------------------------------------
// Kernel 4bc FUSED, barrier-free, PER-WAVE LDS ARENAS + Hs-over-Xs overlay:
// grid 512, block 256. Each wave owns a private 8704 B arena holding its
// 32 Xs rows [32][136]; after af2 + register-residual are extracted, the
// arena's base is reused as Hs[32][40]. LDS 34816 B -> 4 blocks/CU.
// LN1 output kept BOTH in Xs (for A-frags) and packed bf16 registers
// (for LN2 residual) -> bit-identical math to round 15/16/17.
// ---------------------------------------------------------------------------
__global__ __launch_bounds__(256, 4) void proj_ffn_kernel(const bf16* __restrict__ SRC,
    short* __restrict__ Xb, const short* __restrict__ WoT,
    const float* __restrict__ bo, const float* __restrict__ g1v,
    const float* __restrict__ bb1,
    const short* __restrict__ W1T, const float* __restrict__ bf1,
    const short* __restrict__ W2T, const float* __restrict__ bf2,
    const float* __restrict__ g2v, const float* __restrict__ bb2)
{
  __shared__ __align__(16) short lds_arena[4*4352];   // 34816 B total
  const int n = blockIdx.x, tid = threadIdx.x;
  const int wid = tid >> 6, lane = tid & 63;
  const int l15 = lane & 15, quad = lane >> 4;
  short* Xs = lds_arena + wid*4352;   // this wave's [32][136]
  short* Hs = lds_arena + wid*4352;   // overlays own Xs AFTER af2/rres extracted
  const short* an = (const short*)SRC + (size_t)n*16384;
  short* xn = Xb + (size_t)n*16384;

  // ======== phase 1: proj GEMM ========
  f32x4 Y[2][8];
  #pragma unroll
  for (int mi = 0; mi < 2; mi++)
    #pragma unroll
    for (int nt = 0; nt < 8; nt++){ f32x4 z = {0.f,0.f,0.f,0.f}; Y[mi][nt] = z; }

  #pragma unroll
  for (int ks = 0; ks < 4; ks++){
    short8 af[2];
    #pragma unroll
    for (int mi = 0; mi < 2; mi++){
      int row = (wid*2 + mi)*16 + l15;
      af[mi] = *(const short8*)(an + row*128 + ks*32 + quad*8);
    }
    #pragma unroll
    for (int nt = 0; nt < 8; nt++){
      int coln = nt*16 + l15;
      short8 bh = *(const short8*)(WoT + coln*128 + ks*32 + quad*8);
      #pragma unroll
      for (int mi = 0; mi < 2; mi++)
        Y[mi][nt] = __builtin_amdgcn_mfma_f32_16x16x32_bf16(af[mi], bh, Y[mi][nt], 0, 0, 0);
    }
  }

  // ======== phase 2: LN1 -> Xs (wave arena) + packed register residual ========
  unsigned int rres[2][4][4];
  {
    float bov[8], gv[8], bbv[8];
    #pragma unroll
    for (int nt = 0; nt < 8; nt++){
      int col = nt*16 + l15;
      bov[nt] = bo[col]; gv[nt] = g1v[col]; bbv[nt] = bb1[col];
    }
    #pragma unroll
    for (int mi = 0; mi < 2; mi++){
      #pragma unroll
      for (int r = 0; r < 4; r++){
        int grow = (wid*2 + mi)*16 + quad*4 + r;   // global row for residual read
        int lr   = mi*16 + quad*4 + r;             // arena-local row
        float yv[8]; float S = 0.f, Q = 0.f;
        #pragma unroll
        for (int nt = 0; nt < 8; nt++){
          int col = nt*16 + l15;
          float y = Y[mi][nt][r] + bov[nt] + bs2f(xn[grow*128 + col]);
          yv[nt] = y; S += y; Q += y*y;
        }
        #pragma unroll
        for (int o = 1; o < 16; o <<= 1){ S += __shfl_xor(S, o, 64); Q += __shfl_xor(Q, o, 64); }
        float m = S * (1.f/128.f);
        float var = Q * (1.f/128.f) - m*m;
        float inv = rsqrtf(var + 1e-5f);
        short hv[8];
        #pragma unroll
        for (int nt = 0; nt < 8; nt++){
          int col = nt*16 + l15;
          hv[nt] = f2bs((yv[nt] - m) * inv * gv[nt] + bbv[nt]);
          Xs[lr*136 + col] = hv[nt];
        }
        #pragma unroll
        for (int j = 0; j < 4; j++)
          rres[mi][r][j] = (unsigned int)(unsigned short)hv[2*j]
                         | ((unsigned int)(unsigned short)hv[2*j+1] << 16);
      }
    }
  }

  // ======== phase 3a: A-frags from Xs (arena), then Xs is dead ========
  short8 af2[2][4];
  #pragma unroll
  for (int mi = 0; mi < 2; mi++){
    int lr = mi*16 + l15;
    #pragma unroll
    for (int ks = 0; ks < 4; ks++)
      af2[mi][ks] = *(const short8*)(Xs + lr*136 + ks*32 + quad*8);
  }

  // ======== phase 3b: FFN, FF chunked by 32 cols, Hs overlays own Xs ========
  f32x4 Y2[2][8];
  #pragma unroll
  for (int mi = 0; mi < 2; mi++)
    #pragma unroll
    for (int nt = 0; nt < 8; nt++){ f32x4 z = {0.f,0.f,0.f,0.f}; Y2[mi][nt] = z; }

  for (int c = 0; c < 16; c++){
    f32x4 Hc[2][2];
    #pragma unroll
    for (int mi = 0; mi < 2; mi++)
      #pragma unroll
      for (int nt = 0; nt < 2; nt++){ f32x4 z = {0.f,0.f,0.f,0.f}; Hc[mi][nt] = z; }
    #pragma unroll
    for (int ks = 0; ks < 4; ks++){
      #pragma unroll
      for (int nt = 0; nt < 2; nt++){
        int colg = c*32 + nt*16 + l15;
        short8 bh = *(const short8*)(W1T + colg*128 + ks*32 + quad*8);
        #pragma unroll
        for (int mi = 0; mi < 2; mi++)
          Hc[mi][nt] = __builtin_amdgcn_mfma_f32_16x16x32_bf16(af2[mi][ks], bh, Hc[mi][nt], 0, 0, 0);
      }
    }
    #pragma unroll
    for (int nt = 0; nt < 2; nt++){
      int col = nt*16 + l15;
      float b1v = bf1[c*32 + col];
      #pragma unroll
      for (int mi = 0; mi < 2; mi++){
        int lrb = mi*16 + quad*4;
        #pragma unroll
        for (int r = 0; r < 4; r++)
          Hs[(lrb + r)*40 + col] = f2bs(fmaxf(Hc[mi][nt][r] + b1v, 0.f));
      }
    }
    short8 ph[2];
    #pragma unroll
    for (int mi = 0; mi < 2; mi++){
      int lr = mi*16 + l15;
      ph[mi] = *(const short8*)(Hs + lr*40 + quad*8);
    }
    #pragma unroll
    for (int nt = 0; nt < 8; nt++){
      int coln = nt*16 + l15;
      short8 bh = *(const short8*)(W2T + coln*512 + c*32 + quad*8);
      #pragma unroll
      for (int mi = 0; mi < 2; mi++)
        Y2[mi][nt] = __builtin_amdgcn_mfma_f32_16x16x32_bf16(ph[mi], bh, Y2[mi][nt], 0, 0, 0);
    }
  }

  // ======== phase 4: LN2 -> Xb. residual from packed registers. ========
  {
    float b2v[8], gv[8], bbv[8];
    #pragma unroll
    for (int nt = 0; nt < 8; nt++){
      int col = nt*16 + l15;
      b2v[nt] = bf2[col]; gv[nt] = g2v[col]; bbv[nt] = bb2[col];
    }
    #pragma unroll
    for (int mi = 0; mi < 2; mi++){
      #pragma unroll
      for (int r = 0; r < 4; r++){
        int grow = (wid*2 + mi)*16 + quad*4 + r;
        float yv[8]; float S = 0.f, Q = 0.f;
        #pragma unroll
        for (int nt = 0; nt < 8; nt++){
          unsigned int pk = rres[mi][r][nt >> 1];
          short hvv = (nt & 1) ? (short)(pk >> 16) : (short)(pk & 0xFFFF);
          float y = Y2[mi][nt][r] + b2v[nt] + bs2f(hvv);
          yv[nt] = y; S += y; Q += y*y;
        }
        #pragma unroll
        for (int o = 1; o < 16; o <<= 1){ S += __shfl_xor(S, o, 64); Q += __shfl_xor(Q, o, 64); }
        float m = S * (1.f/128.f);
        float var = Q * (1.f/128.f) - m*m;
        float inv = rsqrtf(var + 1e-5f);
        #pragma unroll
        for (int nt = 0; nt < 8; nt++){
          int col = nt*16 + l15;
          xn[grow*128 + col] = f2bs((yv[nt] - m) * inv * gv[nt] + bbv[nt]);
        }
      }
    }
  }
}

// ---------------------------------------------------------------------------
// Kernel 5a: normalize measurement vectors. grid 128, block 128.
// ---------------------------------------------------------------------------
__global__ void meas_norm_kernel(const float* mr, const float* mi, float* VMEAS,
                                 short* VMEASB)
{
  __shared__ float red[2];
  int k = blockIdx.x, tid = threadIdx.x;
  float a = mr[k*128 + tid], b = mi[k*128 + tid];
  float ws = wred_sum(a*a + b*b);
  int wid = tid >> 6, lane = tid & 63;
  if (lane == 0) red[wid] = ws;
  __syncthreads();
  float inv = 1.f / fmaxf(sqrtf(red[0] + red[1]), 1e-12f);
  float vr = a * inv, vi = b * inv;
  int i = k*128 + tid;
  VMEAS[i]          = vr;
  VMEAS[16384 + i]  = vi;
  VMEASB[i]         = f2bs(vr);
  VMEASB[16384 + i] = f2bs(vi);
  VMEASB[32768 + i] = f2bs(-vi);
}

// ---------------------------------------------------------------------------
// Kernel 5b: probs[k] = Re(v_k^dag rho v_k) via MFMA.
// ---------------------------------------------------------------------------
__global__ __launch_bounds__(256) void probs_kernel(const short* __restrict__ Xb,
    const float* __restrict__ VMEAS, const short* __restrict__ VMEASB,
    float* __restrict__ PROBS)
{
  __shared__ float sp[128];
  const int bt = blockIdx.x, z = blockIdx.y, tid = threadIdx.x;
  const int wid = tid >> 6, lane = tid & 63;
  const int l15 = lane & 15, quad = lane >> 4;
  const short* R = Xb + (size_t)bt*16384;
  const short* I = Xb + (size_t)(256+bt)*16384;
  const short* vrB  = VMEASB;
  const short* viB  = VMEASB + 16384;
  const short* nviB = VMEASB + 32768;

  if (tid < 128) sp[tid] = 0.f;
  __syncthreads();

  const int drow = z*64 + wid*16 + l15;
  short8 aR[4], aI[4];
  #pragma unroll
  for (int ks = 0; ks < 4; ks++){
    aR[ks] = *(const short8*)(R + drow*128 + ks*32 + quad*8);
    aI[ks] = *(const short8*)(I + drow*128 + ks*32 + quad*8);
  }

  float p[8];
  #pragma unroll
  for (int nt = 0; nt < 8; nt++) p[nt] = 0.f;
  const int db = z*64 + wid*16 + quad*4;

  {
    f32x4 Ar[8];
    #pragma unroll
    for (int nt = 0; nt < 8; nt++){ f32x4 zz = {0.f,0.f,0.f,0.f}; Ar[nt] = zz; }
    #pragma unroll
    for (int ks = 0; ks < 4; ks++){
      #pragma unroll
      for (int nt = 0; nt < 8; nt++){
        int coln = nt*16 + l15;
        short8 b1 = *(const short8*)(vrB  + coln*128 + ks*32 + quad*8);
        short8 b2 = *(const short8*)(nviB + coln*128 + ks*32 + quad*8);
        Ar[nt] = __builtin_amdgcn_mfma_f32_16x16x32_bf16(aR[ks], b1, Ar[nt], 0, 0, 0);
        Ar[nt] = __builtin_amdgcn_mfma_f32_16x16x32_bf16(aI[ks], b2, Ar[nt], 0, 0, 0);
      }
    }
    #pragma unroll
    for (int nt = 0; nt < 8; nt++){
      int k = nt*16 + l15;
      #pragma unroll
      for (int r = 0; r < 4; r++)
        p[nt] = fmaf(VMEAS[k*128 + db + r], Ar[nt][r], p[nt]);
    }
  }
  {
    f32x4 Ai[8];
    #pragma unroll
    for (int nt = 0; nt < 8; nt++){ f32x4 zz = {0.f,0.f,0.f,0.f}; Ai[nt] = zz; }
    #pragma unroll
    for (int ks = 0; ks < 4; ks++){
      #pragma unroll
      for (int nt = 0; nt < 8; nt++){
        int coln = nt*16 + l15;
        short8 b1 = *(const short8*)(viB + coln*128 + ks*32 + quad*8);
        short8 b2 = *(const short8*)(vrB + coln*128 + ks*32 + quad*8);
        Ai[nt] = __builtin_amdgcn_mfma_f32_16x16x32_bf16(aR[ks], b1, Ai[nt], 0, 0, 0);
        Ai[nt] = __builtin_amdgcn_mfma_f32_16x16x32_bf16(aI[ks], b2, Ai[nt], 0, 0, 0);
      }
    }
    #pragma unroll
    for (int nt = 0; nt < 8; nt++){
      int k = nt*16 + l15;
      #pragma unroll
      for (int r = 0; r < 4; r++)
        p[nt] = fmaf(VMEAS[16384 + k*128 + db + r], Ai[nt][r], p[nt]);
    }
  }

  #pragma unroll
  for (int nt = 0; nt < 8; nt++){
    float v = p[nt];
    v += __shfl_xor(v, 16, 64);
    v += __shfl_xor(v, 32, 64);
    if (quad == 0) atomicAdd(&sp[nt*16 + l15], v);
  }
  __syncthreads();
  if (tid < 128) PROBS[(size_t)(z*256 + bt)*128 + tid] = sp[tid];
}

// ---------------------------------------------------------------------------
// Kernel 6: classifier head + log_softmax. grid 256, block 64.
// ---------------------------------------------------------------------------
__global__ void head_kernel(const float* PROBS, const float* W1, const float* b1,
                            const float* W2, const float* b2, float* out)
{
  __shared__ float h[64];
  __shared__ float lg[7];
  __shared__ float mred[2];
  int bt = blockIdx.x, tid = threadIdx.x;
  float a0 = b1[tid], a1 = 0.f, a2 = 0.f, a3 = 0.f;
  for (int d = 0; d < 128; d += 4){
    float p0 = PROBS[bt*128 + d  ] + PROBS[(256+bt)*128 + d  ];
    float p1 = PROBS[bt*128 + d+1] + PROBS[(256+bt)*128 + d+1];
    float p2 = PROBS[bt*128 + d+2] + PROBS[(256+bt)*128 + d+2];
    float p3 = PROBS[bt*128 + d+3] + PROBS[(256+bt)*128 + d+3];
    a0 = fmaf(p0, W1[(d  )*64 + tid], a0);
    a1 = fmaf(p1, W1[(d+1)*64 + tid], a1);
    a2 = fmaf(p2, W1[(d+2)*64 + tid], a2);
    a3 = fmaf(p3, W1[(d+3)*64 + tid], a3);
  }
  h[tid] = fmaxf((a0 + a1) + (a2 + a3), 0.f);
  __syncthreads();
  if (tid < 7){
    float a = b2[tid];
    for (int j = 0; j < 64; j++) a = fmaf(h[j], W2[j*7 + tid], a);
    lg[tid] = a;
  }
  __syncthreads();
  if (tid == 0){
    float M = -1e30f;
    for (int c = 0; c < 7; c++) M = fmaxf(M, lg[c]);
    float S = 0.f;
    for (int c = 0; c < 7; c++) S += __expf(lg[c] - M);
    mred[0] = M; mred[1] = logf(S);
  }
  __syncthreads();
  if (tid < 7) out[bt*7 + tid] = lg[tid] - mred[0] - mred[1];
}

// ---------------------------------------------------------------------------
extern "C" void kernel_launch(void* const* d_in, const int* in_sizes, int n_in,
                              void* d_out, int out_size, void* d_ws, size_t ws_size,
                              hipStream_t stream)
{
  (void)in_sizes; (void)n_in; (void)out_size; (void)ws_size;
  const float* xt   = (const float*)d_in[0];
  const float* xv   = (const float*)d_in[1];
  const float* xa   = (const float*)d_in[2];
  const float* Wpt  = (const float*)d_in[3];
  const float* bpt  = (const float*)d_in[4];
  const float* Wpv  = (const float*)d_in[5];
  const float* bpv  = (const float*)d_in[6];
  const float* Wpa  = (const float*)d_in[7];
  const float* bpa  = (const float*)d_in[8];
  const float* l1   = (const float*)d_in[9];
  const float* l2   = (const float*)d_in[10];
  const float* Wl1  = (const float*)d_in[11];
  const float* bl1  = (const float*)d_in[12];
  const float* Wl2  = (const float*)d_in[13];
  const float* bl2  = (const float*)d_in[14];
  const float* pht  = (const float*)d_in[15];
  const float* phv  = (const float*)d_in[16];
  const float* pha  = (const float*)d_in[17];
  const float* Wqkv = (const float*)d_in[18];
  const float* bqkv = (const float*)d_in[19];
  const float* Wo   = (const float*)d_in[20];
  const float* bo   = (const float*)d_in[21];
  const float* g1   = (const float*)d_in[22];
  const float* b1   = (const float*)d_in[23];
  const float* W1   = (const float*)d_in[24];
  const float* bf1  = (const float*)d_in[25];
  const float* W2   = (const float*)d_in[26];
  const float* bf2  = (const float*)d_in[27];
  const float* g2   = (const float*)d_in[28];
  const float* b2   = (const float*)d_in[29];
  const float* mr   = (const float*)d_in[30];
  const float* mi   = (const float*)d_in[31];
  const float* fcW1 = (const float*)d_in[32];
  const float* fcb1 = (const float*)d_in[33];
  const float* fcW2 = (const float*)d_in[34];
  const float* fcb2 = (const float*)d_in[35];
  float* out = (float*)d_out;

  // workspace layout (bytes) -- total ~34 MiB. All transposed weights = 2 layers.
  char* wsb = (char*)d_ws;
  short* Xb     = (short*)(wsb);                        // 16777216 B (bf16 X stream)
  bf16*  ATTO   = (bf16*) (wsb + 16777216);             // 16777216 B
  float* PURE   = (float*)(wsb + 33554432);             // 786432 B
  float* RNORM  = (float*)(wsb + 34340864);             // 4096 B
  float* LANGB  = (float*)(wsb + 34344960);             // 2048 B
  float* VMEAS  = (float*)(wsb + 34347008);             // 131072 B
  float* PROBS  = (float*)(wsb + 34478080);             // 262144 B
  short* WqkvT  = (short*)(wsb + 34740224);             // 196608 B
  short* WoT    = (short*)(wsb + 34936832);             // 65536 B
  short* W1T    = (short*)(wsb + 35002368);             // 262144 B
  short* W2T    = (short*)(wsb + 35264512);             // 262144 B
  short* VMEASB = (short*)(wsb + 35526656);             // 98304 B

  prep_kernel<<<1153, 128, 0, stream>>>(Wqkv, Wo, W1, W2, WqkvT, WoT, W1T, W2T,
                                        xt, xv, xa, Wpt, bpt, Wpv, bpv, Wpa, bpa,
                                        pht, phv, pha, PURE, RNORM,
                                        l1, l2, Wl1, bl1, Wl2, bl2, LANGB);

  rho_kernel<<<512, 256, 0, stream>>>(PURE, RNORM, LANGB, Xb);

  for (int l = 0; l < 2; l++){
    attn_kernel<<<dim3(512, 4), 256, 0, stream>>>(Xb, WqkvT + (size_t)l*49152,
                                                  bqkv + (size_t)l*384, ATTO);
    proj_ffn_kernel<<<512, 256, 0, stream>>>(ATTO, Xb,
                                             WoT + (size_t)l*16384,
                                             bo + (size_t)l*128, g1 + (size_t)l*128,
                                             b1 + (size_t)l*128,
                                             W1T + (size_t)l*65536, bf1 + (size_t)l*512,
                                             W2T + (size_t)l*65536, bf2 + (size_t)l*128,
                                             g2 + (size_t)l*128, b2 + (size_t)l*128);
  }

  meas_norm_kernel<<<128, 128, 0, stream>>>(mr, mi, VMEAS, VMEASB);
  probs_kernel<<<dim3(256, 2), 256, 0, stream>>>(Xb, VMEAS, VMEASB, PROBS);
  head_kernel<<<256, 64, 0, stream>>>(PROBS, fcW1, fcb1, fcW2, fcb2, out);
}

// Round 19
// 416.028 us; speedup vs baseline: 1.2556x; 1.2556x over previous
//
#include <hip/hip_runtime.h>
#include <hip/hip_bf16.h>

typedef __hip_bfloat16 bf16;
typedef short short8 __attribute__((ext_vector_type(8)));
typedef float f32x4 __attribute__((ext_vector_type(4)));

__device__ __forceinline__ float b2f(bf16 v){ return __bfloat162float(v); }

__device__ __forceinline__ short f2bs(float f){
  union { __hip_bfloat16 b; short s; } u; u.b = __float2bfloat16(f); return u.s;
}
__device__ __forceinline__ float bs2f(short s){
  union { short s; __hip_bfloat16 b; } u; u.s = s; return __bfloat162float(u.b);
}

__device__ __forceinline__ float wred_sum(float v){
  #pragma unroll
  for (int o = 32; o > 0; o >>= 1) v += __shfl_xor(v, o, 64);
  return v;
}

// ---------------------------------------------------------------------------
// modality helper (128 threads)
// ---------------------------------------------------------------------------
template<int DIMN>
__device__ void modality(const float* x, const float* W, const float* bia, const float* ph,
                         float* PURE, float* RNORM, int m, int bt, float* xs, float* red)
{
  int tid = threadIdx.x;
  for (int i = tid; i < DIMN; i += 128) xs[i] = x[bt*DIMN + i];
  __syncthreads();
  float a0 = 0.f, a1 = 0.f, a2 = 0.f, a3 = 0.f;
  int k = 0;
  for (; k + 4 <= DIMN; k += 4){
    a0 = fmaf(xs[k],   W[(k  )*128 + tid], a0);
    a1 = fmaf(xs[k+1], W[(k+1)*128 + tid], a1);
    a2 = fmaf(xs[k+2], W[(k+2)*128 + tid], a2);
    a3 = fmaf(xs[k+3], W[(k+3)*128 + tid], a3);
  }
  for (; k < DIMN; k++) a0 = fmaf(xs[k], W[k*128 + tid], a0);
  float acc = bia[tid] + ((a0 + a1) + (a2 + a3));
  float rep = fmaxf(acc, 0.f);
  float s = wred_sum(rep*rep);
  int wid = tid >> 6, lane = tid & 63;
  if (lane == 0) red[wid] = s;
  __syncthreads();
  float nrm = sqrtf(red[0] + red[1]);
  float amp = rep / fmaxf(nrm, 1e-12f);
  float p = ph[tid];
  PURE[bt*768 + m*128 + tid]       = amp * cosf(p);
  PURE[bt*768 + (3+m)*128 + tid]   = amp * sinf(p);
  if (tid == 0) RNORM[bt*4 + m] = nrm;
}

// ---------------------------------------------------------------------------
// Kernel 0 MERGED PREP: wT (blocks 0..383) + proj (384..1151) + lang (1152).
// block 128 threads.
// ---------------------------------------------------------------------------
__global__ void prep_kernel(
    const float* __restrict__ Wqkv, const float* __restrict__ Wo,
    const float* __restrict__ W1, const float* __restrict__ W2,
    short* __restrict__ WqkvT, short* __restrict__ WoT,
    short* __restrict__ W1T, short* __restrict__ W2T,
    const float* xt, const float* xv, const float* xa,
    const float* Wpt, const float* bpt, const float* Wpv, const float* bpv,
    const float* Wpa, const float* bpa,
    const float* pht, const float* phv, const float* pha,
    float* PURE, float* RNORM,
    const float* l1, const float* l2,
    const float* Wl1, const float* bl1, const float* Wl2, const float* bl2,
    float* LANGB)
{
  __shared__ float xs[600];
  __shared__ float xs2a[300];
  __shared__ float red[4];
  int b = blockIdx.x, tid = threadIdx.x;

  if (b < 384){
    int l = b / 192, bb = b - l*192;
    const float* in; short* out; int K, N, boff;
    if (bb < 48)      { in = Wqkv; out = WqkvT; K = 128; N = 384; boff = bb; }
    else if (bb < 64) { in = Wo;   out = WoT;   K = 128; N = 128; boff = bb - 48; }
    else if (bb < 128){ in = W1;   out = W1T;   K = 128; N = 512; boff = bb - 64; }
    else              { in = W2;   out = W2T;   K = 512; N = 128; boff = bb - 128; }
    int base = l * K * N;
    int i0 = boff * 1024;
    #pragma unroll
    for (int t = 0; t < 8; t++){
      int i = i0 + t*128 + tid;
      if (i < K*N){
        int nn = i / K, kk = i - nn*K;
        out[base + i] = f2bs(in[base + kk*N + nn]);
      }
    }
    return;
  }
  if (b < 1152){
    int idx = b - 384;
    int bt = idx & 255, m = idx >> 8;
    if (m == 0)      modality<600>(xt, Wpt, bpt, pht, PURE, RNORM, 0, bt, xs, red);
    else if (m == 1) modality<342>(xv, Wpv, bpv, phv, PURE, RNORM, 1, bt, xs, red);
    else             modality<300>(xa, Wpa, bpa, pha, PURE, RNORM, 2, bt, xs, red);
    return;
  }
  // ---- lang path (single block) ----
  for (int i = tid; i < 300; i += 128){ xs[i] = l1[i]; xs2a[i] = l2[i]; }
  __syncthreads();
  float p10=0,p11=0,p12=0,p13=0, p20=0,p21=0,p22=0,p23=0;
  for (int k = 0; k < 300; k += 4){
    p10 = fmaf(xs[k],    Wl1[(k  )*128+tid], p10);
    p11 = fmaf(xs[k+1],  Wl1[(k+1)*128+tid], p11);
    p12 = fmaf(xs[k+2],  Wl1[(k+2)*128+tid], p12);
    p13 = fmaf(xs[k+3],  Wl1[(k+3)*128+tid], p13);
    p20 = fmaf(xs2a[k],  Wl2[(k  )*128+tid], p20);
    p21 = fmaf(xs2a[k+1],Wl2[(k+1)*128+tid], p21);
    p22 = fmaf(xs2a[k+2],Wl2[(k+2)*128+tid], p22);
    p23 = fmaf(xs2a[k+3],Wl2[(k+3)*128+tid], p23);
  }
  float a1 = bl1[tid] + ((p10+p11)+(p12+p13));
  float a2 = bl2[tid] + ((p20+p21)+(p22+p23));
  a1 = fmaxf(a1, 0.f); a2 = fmaxf(a2, 0.f);
  int wid = tid >> 6, lane = tid & 63;
  float s1 = wred_sum(a1*a1), s2 = wred_sum(a2*a2);
  if (lane == 0){ red[wid] = s1; red[2+wid] = s2; }
  __syncthreads();
  float n1 = sqrtf(red[0] + red[1]);
  float n2 = sqrtf(red[2] + red[3]);
  float lamp1 = a1 / fmaxf(n1, 1e-12f);
  float lamp2 = a2 / fmaxf(n2, 1e-12f);
  float ph = pht[tid];
  float c = cosf(ph), s = sinf(ph);
  const float s2c = 0.70710678118654752f;
  float h1r = (lamp1*c + lamp1*s)*s2c, h1i = (lamp1*c - lamp1*s)*s2c;
  float h2r = (lamp2*c + lamp2*s)*s2c, h2i = (lamp2*c - lamp2*s)*s2c;
  float er = h1r*h2r - h1i*h2i;
  float ei = h1r*h2i + h1i*h2r;
  __syncthreads();
  float se = wred_sum(er*er + ei*ei);
  if (lane == 0) red[wid] = se;
  __syncthreads();
  float en = fmaxf(sqrtf(red[0] + red[1]), 1e-12f);
  LANGB[tid]       = er / en;
  LANGB[128 + tid] = ei / en;
  if (tid == 0) LANGB[256] = n1;
}

// ---------------------------------------------------------------------------
// Kernel 3: weighted sum of rank-1 density matrices -> Xb (bf16). grid 512.
// ---------------------------------------------------------------------------
__global__ __launch_bounds__(256) void rho_kernel(const float* PURE, const float* RNORM,
                                                  const float* LANGB, short* Xb)
{
  __shared__ float rv[4][128], iv[4][128], wsm[4];
  int bt = blockIdx.x >> 1, half = blockIdx.x & 1;
  int tid = threadIdx.x;
  for (int i = tid; i < 1024; i += 256){
    int d = i & 127;
    if (i < 768){ int m = i >> 7; float v = PURE[bt*768 + i];
                  if (m < 3) rv[m][d] = v; else iv[m-3][d] = v; }
    else if (i < 896) rv[3][d] = LANGB[d];
    else              iv[3][d] = LANGB[128 + d];
  }
  if (tid == 0){
    float n0 = RNORM[bt*4+0], n1 = RNORM[bt*4+1], n2 = RNORM[bt*4+2], n3 = LANGB[256];
    float mx = fmaxf(fmaxf(n0, n1), fmaxf(n2, n3));
    float e0 = __expf(n0-mx), e1 = __expf(n1-mx), e2 = __expf(n2-mx), e3 = __expf(n3-mx);
    float inv = 1.f / (e0+e1+e2+e3);
    wsm[0]=e0*inv; wsm[1]=e1*inv; wsm[2]=e2*inv; wsm[3]=e3*inv;
  }
  __syncthreads();
  float w0 = wsm[0], w1 = wsm[1], w2 = wsm[2], w3 = wsm[3];
  int lo = half*8192, hi = lo + 8192;
  for (int idx = lo + tid; idx < hi; idx += 256){
    int d = idx >> 7, e = idx & 127;
    float rr = 0.f, ri = 0.f;
    {
      float rd=rv[0][d], re=rv[0][e], id=iv[0][d], ie=iv[0][e];
      rr = fmaf(w0, rd*re + id*ie, rr); ri = fmaf(w0, id*re - rd*ie, ri);
    }{
      float rd=rv[1][d], re=rv[1][e], id=iv[1][d], ie=iv[1][e];
      rr = fmaf(w1, rd*re + id*ie, rr); ri = fmaf(w1, id*re - rd*ie, ri);
    }{
      float rd=rv[2][d], re=rv[2][e], id=iv[2][d], ie=iv[2][e];
      rr = fmaf(w2, rd*re + id*ie, rr); ri = fmaf(w2, id*re - rd*ie, ri);
    }{
      float rd=rv[3][d], re=rv[3][e], id=iv[3][d], ie=iv[3][e];
      rr = fmaf(w3, rd*re + id*ie, rr); ri = fmaf(w3, id*re - rd*ie, ri);
    }
    Xb[(size_t)bt*16384 + idx]        = f2bs(rr);
    Xb[(size_t)(256+bt)*16384 + idx]  = f2bs(ri);
  }
}

// ---------------------------------------------------------------------------
// Kernel 4a: fused MHA per (sequence n, head h) via MFMA. grid (512,4), block 256.
// (round-12 version, measured best)
// ---------------------------------------------------------------------------
__global__ __launch_bounds__(256) void attn_kernel(const short* __restrict__ Xb,
    const short* __restrict__ WqkvT, const float* __restrict__ bqkv,
    bf16* __restrict__ ATTO)
{
  __shared__ __align__(16) char lds_raw[43520];
  short* Vt = (short*)(lds_raw);           // [32][136]
  short* Qs = (short*)(lds_raw + 8704);    // [128][40]
  short* Ks = (short*)(lds_raw + 18944);   // [128][40]
  short* Ps = (short*)(lds_raw + 8704);    // [128][136] overlays Qs/Ks

  const int n = blockIdx.x, h = blockIdx.y;
  const int tid = threadIdx.x;
  const int wid = tid >> 6, lane = tid & 63;
  const int l15 = lane & 15, quad = lane >> 4;
  const short* xn = Xb + (size_t)n*16384;

  f32x4 acc[2][6];
  #pragma unroll
  for (int mi = 0; mi < 2; mi++)
    #pragma unroll
    for (int nt = 0; nt < 6; nt++){
      f32x4 z = {0.f, 0.f, 0.f, 0.f}; acc[mi][nt] = z;
    }

  #pragma unroll
  for (int ks = 0; ks < 4; ks++){
    short8 afr[2];
    #pragma unroll
    for (int mi = 0; mi < 2; mi++){
      int row = (wid*2 + mi)*16 + l15;
      afr[mi] = *(const short8*)(xn + row*128 + ks*32 + quad*8);
    }
    #pragma unroll
    for (int nt = 0; nt < 6; nt++){
      int col = (nt >> 1)*128 + h*32 + (nt & 1)*16 + l15;
      short8 bfr = *(const short8*)(WqkvT + (size_t)col*128 + ks*32 + quad*8);
      #pragma unroll
      for (int mi = 0; mi < 2; mi++)
        acc[mi][nt] = __builtin_amdgcn_mfma_f32_16x16x32_bf16(afr[mi], bfr, acc[mi][nt], 0, 0, 0);
    }
  }
  #pragma unroll
  for (int nt = 0; nt < 6; nt++){
    int sec = nt >> 1;
    int cl = (nt & 1)*16 + l15;
    float bias = bqkv[sec*128 + h*32 + cl];
    #pragma unroll
    for (int mi = 0; mi < 2; mi++){
      int rowb = (wid*2 + mi)*16 + quad*4;
      #pragma unroll
      for (int r = 0; r < 4; r++){
        float v = acc[mi][nt][r] + bias;
        int row = rowb + r;
        if (sec == 0)      Qs[row*40 + cl] = f2bs(v * 0.17677669529663687f);
        else if (sec == 1) Ks[row*40 + cl] = f2bs(v);
        else               Vt[cl*136 + row] = f2bs(v);
      }
    }
  }
  __syncthreads();

  f32x4 s[2][8];
  {
    short8 qf[2];
    #pragma unroll
    for (int mi = 0; mi < 2; mi++){
      int row = (wid*2 + mi)*16 + l15;
      qf[mi] = *(const short8*)(Qs + row*40 + quad*8);
    }
    #pragma unroll
    for (int nt = 0; nt < 8; nt++){
      int kr = nt*16 + l15;
      short8 kf = *(const short8*)(Ks + kr*40 + quad*8);
      #pragma unroll
      for (int mi = 0; mi < 2; mi++){
        f32x4 z = {0.f, 0.f, 0.f, 0.f};
        s[mi][nt] = __builtin_amdgcn_mfma_f32_16x16x32_bf16(qf[mi], kf, z, 0, 0, 0);
      }
    }
  }

  #pragma unroll
  for (int mi = 0; mi < 2; mi++){
    #pragma unroll
    for (int r = 0; r < 4; r++){
      float m = -1e30f;
      #pragma unroll
      for (int nt = 0; nt < 8; nt++) m = fmaxf(m, s[mi][nt][r]);
      #pragma unroll
      for (int o = 1; o < 16; o <<= 1) m = fmaxf(m, __shfl_xor(m, o, 64));
      float sum = 0.f;
      #pragma unroll
      for (int nt = 0; nt < 8; nt++){
        float p = __expf(s[mi][nt][r] - m);
        s[mi][nt][r] = p; sum += p;
      }
      #pragma unroll
      for (int o = 1; o < 16; o <<= 1) sum += __shfl_xor(sum, o, 64);
      float inv = 1.f / sum;
      #pragma unroll
      for (int nt = 0; nt < 8; nt++) s[mi][nt][r] *= inv;
    }
  }
  __syncthreads();

  #pragma unroll
  for (int mi = 0; mi < 2; mi++){
    int rowb = (wid*2 + mi)*16 + quad*4;
    #pragma unroll
    for (int nt = 0; nt < 8; nt++){
      int col = nt*16 + l15;
      #pragma unroll
      for (int r = 0; r < 4; r++)
        Ps[(rowb + r)*136 + col] = f2bs(s[mi][nt][r]);
    }
  }
  __syncthreads();

  f32x4 o_[2][2];
  #pragma unroll
  for (int mi = 0; mi < 2; mi++)
    #pragma unroll
    for (int n2 = 0; n2 < 2; n2++){
      f32x4 z = {0.f, 0.f, 0.f, 0.f}; o_[mi][n2] = z;
    }
  #pragma unroll
  for (int ks = 0; ks < 4; ks++){
    short8 pf[2];
    #pragma unroll
    for (int mi = 0; mi < 2; mi++){
      int row = (wid*2 + mi)*16 + l15;
      pf[mi] = *(const short8*)(Ps + row*136 + ks*32 + quad*8);
    }
    #pragma unroll
    for (int n2 = 0; n2 < 2; n2++){
      short8 vf = *(const short8*)(Vt + (n2*16 + l15)*136 + ks*32 + quad*8);
      #pragma unroll
      for (int mi = 0; mi < 2; mi++)
        o_[mi][n2] = __builtin_amdgcn_mfma_f32_16x16x32_bf16(pf[mi], vf, o_[mi][n2], 0, 0, 0);
    }
  }
  bf16* on = ATTO + (size_t)n*16384;
  #pragma unroll
  for (int mi = 0; mi < 2; mi++){
    int rowb = (wid*2 + mi)*16 + quad*4;
    #pragma unroll
    for (int n2 = 0; n2 < 2; n2++){
      int col = h*32 + n2*16 + l15;
      #pragma unroll
      for (int r = 0; r < 4; r++)
        on[(rowb + r)*128 + col] = __float2bfloat16(o_[mi][n2][r]);
    }
  }
}

// ---------------------------------------------------------------------------
// Kernel 4bc FUSED, barrier-free, FF chunked to 32 cols (round-15 version,
// measured best 81 us): grid 512, block 256, LDS 44 KB -> 3 blocks/CU.
// ---------------------------------------------------------------------------
__global__ __launch_bounds__(256, 3) void proj_ffn_kernel(const bf16* __restrict__ SRC,
    short* __restrict__ Xb, const short* __restrict__ WoT,
    const float* __restrict__ bo, const float* __restrict__ g1v,
    const float* __restrict__ bb1,
    const short* __restrict__ W1T, const float* __restrict__ bf1,
    const short* __restrict__ W2T, const float* __restrict__ bf2,
    const float* __restrict__ g2v, const float* __restrict__ bb2)
{
  __shared__ __align__(16) short Xs[128*136];
  __shared__ __align__(16) short Hs[128*40];
  const int n = blockIdx.x, tid = threadIdx.x;
  const int wid = tid >> 6, lane = tid & 63;
  const int l15 = lane & 15, quad = lane >> 4;
  const short* an = (const short*)SRC + (size_t)n*16384;
  short* xn = Xb + (size_t)n*16384;

  f32x4 Y[2][8];
  #pragma unroll
  for (int mi = 0; mi < 2; mi++)
    #pragma unroll
    for (int nt = 0; nt < 8; nt++){ f32x4 z = {0.f,0.f,0.f,0.f}; Y[mi][nt] = z; }

  #pragma unroll
  for (int ks = 0; ks < 4; ks++){
    short8 af[2];
    #pragma unroll
    for (int mi = 0; mi < 2; mi++){
      int row = (wid*2 + mi)*16 + l15;
      af[mi] = *(const short8*)(an + row*128 + ks*32 + quad*8);
    }
    #pragma unroll
    for (int nt = 0; nt < 8; nt++){
      int coln = nt*16 + l15;
      short8 bh = *(const short8*)(WoT + coln*128 + ks*32 + quad*8);
      #pragma unroll
      for (int mi = 0; mi < 2; mi++)
        Y[mi][nt] = __builtin_amdgcn_mfma_f32_16x16x32_bf16(af[mi], bh, Y[mi][nt], 0, 0, 0);
    }
  }

  {
    float bov[8], gv[8], bbv[8];
    #pragma unroll
    for (int nt = 0; nt < 8; nt++){
      int col = nt*16 + l15;
      bov[nt] = bo[col]; gv[nt] = g1v[col]; bbv[nt] = bb1[col];
    }
    #pragma unroll
    for (int mi = 0; mi < 2; mi++){
      #pragma unroll
      for (int r = 0; r < 4; r++){
        int row = (wid*2 + mi)*16 + quad*4 + r;
        float yv[8]; float S = 0.f, Q = 0.f;
        #pragma unroll
        for (int nt = 0; nt < 8; nt++){
          int col = nt*16 + l15;
          float y = Y[mi][nt][r] + bov[nt] + bs2f(xn[row*128 + col]);
          yv[nt] = y; S += y; Q += y*y;
        }
        #pragma unroll
        for (int o = 1; o < 16; o <<= 1){ S += __shfl_xor(S, o, 64); Q += __shfl_xor(Q, o, 64); }
        float m = S * (1.f/128.f);
        float var = Q * (1.f/128.f) - m*m;
        float inv = rsqrtf(var + 1e-5f);
        #pragma unroll
        for (int nt = 0; nt < 8; nt++){
          int col = nt*16 + l15;
          Xs[row*136 + col] = f2bs((yv[nt] - m) * inv * gv[nt] + bbv[nt]);
        }
      }
    }
  }

  short8 af2[2][4];
  #pragma unroll
  for (int mi = 0; mi < 2; mi++){
    int row = (wid*2 + mi)*16 + l15;
    #pragma unroll
    for (int ks = 0; ks < 4; ks++)
      af2[mi][ks] = *(const short8*)(Xs + row*136 + ks*32 + quad*8);
  }

  f32x4 Y2[2][8];
  #pragma unroll
  for (int mi = 0; mi < 2; mi++)
    #pragma unroll
    for (int nt = 0; nt < 8; nt++){ f32x4 z = {0.f,0.f,0.f,0.f}; Y2[mi][nt] = z; }

  for (int c = 0; c < 16; c++){
    f32x4 Hc[2][2];
    #pragma unroll
    for (int mi = 0; mi < 2; mi++)
      #pragma unroll
      for (int nt = 0; nt < 2; nt++){ f32x4 z = {0.f,0.f,0.f,0.f}; Hc[mi][nt] = z; }
    #pragma unroll
    for (int ks = 0; ks < 4; ks++){
      #pragma unroll
      for (int nt = 0; nt < 2; nt++){
        int colg = c*32 + nt*16 + l15;
        short8 bh = *(const short8*)(W1T + colg*128 + ks*32 + quad*8);
        #pragma unroll
        for (int mi = 0; mi < 2; mi++)
          Hc[mi][nt] = __builtin_amdgcn_mfma_f32_16x16x32_bf16(af2[mi][ks], bh, Hc[mi][nt], 0, 0, 0);
      }
    }
    #pragma unroll
    for (int nt = 0; nt < 2; nt++){
      int col = nt*16 + l15;
      float b1v = bf1[c*32 + col];
      #pragma unroll
      for (int mi = 0; mi < 2; mi++){
        int rowb = (wid*2 + mi)*16 + quad*4;
        #pragma unroll
        for (int r = 0; r < 4; r++)
          Hs[(rowb + r)*40 + col] = f2bs(fmaxf(Hc[mi][nt][r] + b1v, 0.f));
      }
    }
    short8 ph[2];
    #pragma unroll
    for (int mi = 0; mi < 2; mi++){
      int row = (wid*2 + mi)*16 + l15;
      ph[mi] = *(const short8*)(Hs + row*40 + quad*8);
    }
    #pragma unroll
    for (int nt = 0; nt < 8; nt++){
      int coln = nt*16 + l15;
      short8 bh = *(const short8*)(W2T + coln*512 + c*32 + quad*8);
      #pragma unroll
      for (int mi = 0; mi < 2; mi++)
        Y2[mi][nt] = __builtin_amdgcn_mfma_f32_16x16x32_bf16(ph[mi], bh, Y2[mi][nt], 0, 0, 0);
    }
  }

  {
    float b2v[8], gv[8], bbv[8];
    #pragma unroll
    for (int nt = 0; nt < 8; nt++){
      int col = nt*16 + l15;
      b2v[nt] = bf2[col]; gv[nt] = g2v[col]; bbv[nt] = bb2[col];
    }
    #pragma unroll
    for (int mi = 0; mi < 2; mi++){
      #pragma unroll
      for (int r = 0; r < 4; r++){
        int row = (wid*2 + mi)*16 + quad*4 + r;
        float yv[8]; float S = 0.f, Q = 0.f;
        #pragma unroll
        for (int nt = 0; nt < 8; nt++){
          int col = nt*16 + l15;
          float y = Y2[mi][nt][r] + b2v[nt] + bs2f(Xs[row*136 + col]);
          yv[nt] = y; S += y; Q += y*y;
        }
        #pragma unroll
        for (int o = 1; o < 16; o <<= 1){ S += __shfl_xor(S, o, 64); Q += __shfl_xor(Q, o, 64); }
        float m = S * (1.f/128.f);
        float var = Q * (1.f/128.f) - m*m;
        float inv = rsqrtf(var + 1e-5f);
        #pragma unroll
        for (int nt = 0; nt < 8; nt++){
          int col = nt*16 + l15;
          xn[row*128 + col] = f2bs((yv[nt] - m) * inv * gv[nt] + bbv[nt]);
        }
      }
    }
  }
}

// ---------------------------------------------------------------------------
// Kernel 5a: normalize measurement vectors. grid 128, block 128.
// ---------------------------------------------------------------------------
__global__ void meas_norm_kernel(const float* mr, const float* mi, float* VMEAS,
                                 short* VMEASB)
{
  __shared__ float red[2];
  int k = blockIdx.x, tid = threadIdx.x;
  float a = mr[k*128 + tid], b = mi[k*128 + tid];
  float ws = wred_sum(a*a + b*b);
  int wid = tid >> 6, lane = tid & 63;
  if (lane == 0) red[wid] = ws;
  __syncthreads();
  float inv = 1.f / fmaxf(sqrtf(red[0] + red[1]), 1e-12f);
  float vr = a * inv, vi = b * inv;
  int i = k*128 + tid;
  VMEAS[i]          = vr;
  VMEAS[16384 + i]  = vi;
  VMEASB[i]         = f2bs(vr);
  VMEASB[16384 + i] = f2bs(vi);
  VMEASB[32768 + i] = f2bs(-vi);
}

// ---------------------------------------------------------------------------
// Kernel 5b: probs[k] = Re(v_k^dag rho v_k) via MFMA.
// ---------------------------------------------------------------------------
__global__ __launch_bounds__(256) void probs_kernel(const short* __restrict__ Xb,
    const float* __restrict__ VMEAS, const short* __restrict__ VMEASB,
    float* __restrict__ PROBS)
{
  __shared__ float sp[128];
  const int bt = blockIdx.x, z = blockIdx.y, tid = threadIdx.x;
  const int wid = tid >> 6, lane = tid & 63;
  const int l15 = lane & 15, quad = lane >> 4;
  const short* R = Xb + (size_t)bt*16384;
  const short* I = Xb + (size_t)(256+bt)*16384;
  const short* vrB  = VMEASB;
  const short* viB  = VMEASB + 16384;
  const short* nviB = VMEASB + 32768;

  if (tid < 128) sp[tid] = 0.f;
  __syncthreads();

  const int drow = z*64 + wid*16 + l15;
  short8 aR[4], aI[4];
  #pragma unroll
  for (int ks = 0; ks < 4; ks++){
    aR[ks] = *(const short8*)(R + drow*128 + ks*32 + quad*8);
    aI[ks] = *(const short8*)(I + drow*128 + ks*32 + quad*8);
  }

  float p[8];
  #pragma unroll
  for (int nt = 0; nt < 8; nt++) p[nt] = 0.f;
  const int db = z*64 + wid*16 + quad*4;

  {
    f32x4 Ar[8];
    #pragma unroll
    for (int nt = 0; nt < 8; nt++){ f32x4 zz = {0.f,0.f,0.f,0.f}; Ar[nt] = zz; }
    #pragma unroll
    for (int ks = 0; ks < 4; ks++){
      #pragma unroll
      for (int nt = 0; nt < 8; nt++){
        int coln = nt*16 + l15;
        short8 b1 = *(const short8*)(vrB  + coln*128 + ks*32 + quad*8);
        short8 b2 = *(const short8*)(nviB + coln*128 + ks*32 + quad*8);
        Ar[nt] = __builtin_amdgcn_mfma_f32_16x16x32_bf16(aR[ks], b1, Ar[nt], 0, 0, 0);
        Ar[nt] = __builtin_amdgcn_mfma_f32_16x16x32_bf16(aI[ks], b2, Ar[nt], 0, 0, 0);
      }
    }
    #pragma unroll
    for (int nt = 0; nt < 8; nt++){
      int k = nt*16 + l15;
      #pragma unroll
      for (int r = 0; r < 4; r++)
        p[nt] = fmaf(VMEAS[k*128 + db + r], Ar[nt][r], p[nt]);
    }
  }
  {
    f32x4 Ai[8];
    #pragma unroll
    for (int nt = 0; nt < 8; nt++){ f32x4 zz = {0.f,0.f,0.f,0.f}; Ai[nt] = zz; }
    #pragma unroll
    for (int ks = 0; ks < 4; ks++){
      #pragma unroll
      for (int nt = 0; nt < 8; nt++){
        int coln = nt*16 + l15;
        short8 b1 = *(const short8*)(viB + coln*128 + ks*32 + quad*8);
        short8 b2 = *(const short8*)(vrB + coln*128 + ks*32 + quad*8);
        Ai[nt] = __builtin_amdgcn_mfma_f32_16x16x32_bf16(aR[ks], b1, Ai[nt], 0, 0, 0);
        Ai[nt] = __builtin_amdgcn_mfma_f32_16x16x32_bf16(aI[ks], b2, Ai[nt], 0, 0, 0);
      }
    }
    #pragma unroll
    for (int nt = 0; nt < 8; nt++){
      int k = nt*16 + l15;
      #pragma unroll
      for (int r = 0; r < 4; r++)
        p[nt] = fmaf(VMEAS[16384 + k*128 + db + r], Ai[nt][r], p[nt]);
    }
  }

  #pragma unroll
  for (int nt = 0; nt < 8; nt++){
    float v = p[nt];
    v += __shfl_xor(v, 16, 64);
    v += __shfl_xor(v, 32, 64);
    if (quad == 0) atomicAdd(&sp[nt*16 + l15], v);
  }
  __syncthreads();
  if (tid < 128) PROBS[(size_t)(z*256 + bt)*128 + tid] = sp[tid];
}

// ---------------------------------------------------------------------------
// Kernel 6: classifier head + log_softmax. grid 256, block 64.
// ---------------------------------------------------------------------------
__global__ void head_kernel(const float* PROBS, const float* W1, const float* b1,
                            const float* W2, const float* b2, float* out)
{
  __shared__ float h[64];
  __shared__ float lg[7];
  __shared__ float mred[2];
  int bt = blockIdx.x, tid = threadIdx.x;
  float a0 = b1[tid], a1 = 0.f, a2 = 0.f, a3 = 0.f;
  for (int d = 0; d < 128; d += 4){
    float p0 = PROBS[bt*128 + d  ] + PROBS[(256+bt)*128 + d  ];
    float p1 = PROBS[bt*128 + d+1] + PROBS[(256+bt)*128 + d+1];
    float p2 = PROBS[bt*128 + d+2] + PROBS[(256+bt)*128 + d+2];
    float p3 = PROBS[bt*128 + d+3] + PROBS[(256+bt)*128 + d+3];
    a0 = fmaf(p0, W1[(d  )*64 + tid], a0);
    a1 = fmaf(p1, W1[(d+1)*64 + tid], a1);
    a2 = fmaf(p2, W1[(d+2)*64 + tid], a2);
    a3 = fmaf(p3, W1[(d+3)*64 + tid], a3);
  }
  h[tid] = fmaxf((a0 + a1) + (a2 + a3), 0.f);
  __syncthreads();
  if (tid < 7){
    float a = b2[tid];
    for (int j = 0; j < 64; j++) a = fmaf(h[j], W2[j*7 + tid], a);
    lg[tid] = a;
  }
  __syncthreads();
  if (tid == 0){
    float M = -1e30f;
    for (int c = 0; c < 7; c++) M = fmaxf(M, lg[c]);
    float S = 0.f;
    for (int c = 0; c < 7; c++) S += __expf(lg[c] - M);
    mred[0] = M; mred[1] = logf(S);
  }
  __syncthreads();
  if (tid < 7) out[bt*7 + tid] = lg[tid] - mred[0] - mred[1];
}

// ---------------------------------------------------------------------------
extern "C" void kernel_launch(void* const* d_in, const int* in_sizes, int n_in,
                              void* d_out, int out_size, void* d_ws, size_t ws_size,
                              hipStream_t stream)
{
  (void)in_sizes; (void)n_in; (void)out_size; (void)ws_size;
  const float* xt   = (const float*)d_in[0];
  const float* xv   = (const float*)d_in[1];
  const float* xa   = (const float*)d_in[2];
  const float* Wpt  = (const float*)d_in[3];
  const float* bpt  = (const float*)d_in[4];
  const float* Wpv  = (const float*)d_in[5];
  const float* bpv  = (const float*)d_in[6];
  const float* Wpa  = (const float*)d_in[7];
  const float* bpa  = (const float*)d_in[8];
  const float* l1   = (const float*)d_in[9];
  const float* l2   = (const float*)d_in[10];
  const float* Wl1  = (const float*)d_in[11];
  const float* bl1  = (const float*)d_in[12];
  const float* Wl2  = (const float*)d_in[13];
  const float* bl2  = (const float*)d_in[14];
  const float* pht  = (const float*)d_in[15];
  const float* phv  = (const float*)d_in[16];
  const float* pha  = (const float*)d_in[17];
  const float* Wqkv = (const float*)d_in[18];
  const float* bqkv = (const float*)d_in[19];
  const float* Wo   = (const float*)d_in[20];
  const float* bo   = (const float*)d_in[21];
  const float* g1   = (const float*)d_in[22];
  const float* b1   = (const float*)d_in[23];
  const float* W1   = (const float*)d_in[24];
  const float* bf1  = (const float*)d_in[25];
  const float* W2   = (const float*)d_in[26];
  const float* bf2  = (const float*)d_in[27];
  const float* g2   = (const float*)d_in[28];
  const float* b2   = (const float*)d_in[29];
  const float* mr   = (const float*)d_in[30];
  const float* mi   = (const float*)d_in[31];
  const float* fcW1 = (const float*)d_in[32];
  const float* fcb1 = (const float*)d_in[33];
  const float* fcW2 = (const float*)d_in[34];
  const float* fcb2 = (const float*)d_in[35];
  float* out = (float*)d_out;

  // workspace layout (bytes) -- total ~34 MiB. All transposed weights = 2 layers.
  char* wsb = (char*)d_ws;
  short* Xb     = (short*)(wsb);                        // 16777216 B (bf16 X stream)
  bf16*  ATTO   = (bf16*) (wsb + 16777216);             // 16777216 B
  float* PURE   = (float*)(wsb + 33554432);             // 786432 B
  float* RNORM  = (float*)(wsb + 34340864);             // 4096 B
  float* LANGB  = (float*)(wsb + 34344960);             // 2048 B
  float* VMEAS  = (float*)(wsb + 34347008);             // 131072 B
  float* PROBS  = (float*)(wsb + 34478080);             // 262144 B
  short* WqkvT  = (short*)(wsb + 34740224);             // 196608 B
  short* WoT    = (short*)(wsb + 34936832);             // 65536 B
  short* W1T    = (short*)(wsb + 35002368);             // 262144 B
  short* W2T    = (short*)(wsb + 35264512);             // 262144 B
  short* VMEASB = (short*)(wsb + 35526656);             // 98304 B

  prep_kernel<<<1153, 128, 0, stream>>>(Wqkv, Wo, W1, W2, WqkvT, WoT, W1T, W2T,
                                        xt, xv, xa, Wpt, bpt, Wpv, bpv, Wpa, bpa,
                                        pht, phv, pha, PURE, RNORM,
                                        l1, l2, Wl1, bl1, Wl2, bl2, LANGB);

  rho_kernel<<<512, 256, 0, stream>>>(PURE, RNORM, LANGB, Xb);

  for (int l = 0; l < 2; l++){
    attn_kernel<<<dim3(512, 4), 256, 0, stream>>>(Xb, WqkvT + (size_t)l*49152,
                                                  bqkv + (size_t)l*384, ATTO);
    proj_ffn_kernel<<<512, 256, 0, stream>>>(ATTO, Xb,
                                             WoT + (size_t)l*16384,
                                             bo + (size_t)l*128, g1 + (size_t)l*128,
                                             b1 + (size_t)l*128,
                                             W1T + (size_t)l*65536, bf1 + (size_t)l*512,
                                             W2T + (size_t)l*65536, bf2 + (size_t)l*128,
                                             g2 + (size_t)l*128, b2 + (size_t)l*128);
  }

  meas_norm_kernel<<<128, 128, 0, stream>>>(mr, mi, VMEAS, VMEASB);
  probs_kernel<<<dim3(256, 2), 256, 0, stream>>>(Xb, VMEAS, VMEASB, PROBS);
  head_kernel<<<256, 64, 0, stream>>>(PROBS, fcW1, fcb1, fcW2, fcb2, out);
}

// Round 20
// 415.273 us; speedup vs baseline: 1.2578x; 1.0018x over previous
//
#include <hip/hip_runtime.h>
#include <hip/hip_bf16.h>

typedef __hip_bfloat16 bf16;
typedef short short8 __attribute__((ext_vector_type(8)));
typedef float f32x4 __attribute__((ext_vector_type(4)));

__device__ __forceinline__ float b2f(bf16 v){ return __bfloat162float(v); }

__device__ __forceinline__ short f2bs(float f){
  union { __hip_bfloat16 b; short s; } u; u.b = __float2bfloat16(f); return u.s;
}
__device__ __forceinline__ float bs2f(short s){
  union { short s; __hip_bfloat16 b; } u; u.s = s; return __bfloat162float(u.b);
}

__device__ __forceinline__ float wred_sum(float v){
  #pragma unroll
  for (int o = 32; o > 0; o >>= 1) v += __shfl_xor(v, o, 64);
  return v;
}

// ---------------------------------------------------------------------------
// modality helper (128 threads)
// ---------------------------------------------------------------------------
template<int DIMN>
__device__ void modality(const float* x, const float* W, const float* bia, const float* ph,
                         float* PURE, float* RNORM, int m, int bt, float* xs, float* red)
{
  int tid = threadIdx.x;
  for (int i = tid; i < DIMN; i += 128) xs[i] = x[bt*DIMN + i];
  __syncthreads();
  float a0 = 0.f, a1 = 0.f, a2 = 0.f, a3 = 0.f;
  int k = 0;
  for (; k + 4 <= DIMN; k += 4){
    a0 = fmaf(xs[k],   W[(k  )*128 + tid], a0);
    a1 = fmaf(xs[k+1], W[(k+1)*128 + tid], a1);
    a2 = fmaf(xs[k+2], W[(k+2)*128 + tid], a2);
    a3 = fmaf(xs[k+3], W[(k+3)*128 + tid], a3);
  }
  for (; k < DIMN; k++) a0 = fmaf(xs[k], W[k*128 + tid], a0);
  float acc = bia[tid] + ((a0 + a1) + (a2 + a3));
  float rep = fmaxf(acc, 0.f);
  float s = wred_sum(rep*rep);
  int wid = tid >> 6, lane = tid & 63;
  if (lane == 0) red[wid] = s;
  __syncthreads();
  float nrm = sqrtf(red[0] + red[1]);
  float amp = rep / fmaxf(nrm, 1e-12f);
  float p = ph[tid];
  PURE[bt*768 + m*128 + tid]       = amp * cosf(p);
  PURE[bt*768 + (3+m)*128 + tid]   = amp * sinf(p);
  if (tid == 0) RNORM[bt*4 + m] = nrm;
}

// ---------------------------------------------------------------------------
// Kernel 0 MERGED PREP: wT (blocks 0..383) + proj (384..1151) + lang (1152)
// + meas_norm (1153..1280, independent of everything else in prep).
// block 128 threads.
// ---------------------------------------------------------------------------
__global__ void prep_kernel(
    const float* __restrict__ Wqkv, const float* __restrict__ Wo,
    const float* __restrict__ W1, const float* __restrict__ W2,
    short* __restrict__ WqkvT, short* __restrict__ WoT,
    short* __restrict__ W1T, short* __restrict__ W2T,
    const float* xt, const float* xv, const float* xa,
    const float* Wpt, const float* bpt, const float* Wpv, const float* bpv,
    const float* Wpa, const float* bpa,
    const float* pht, const float* phv, const float* pha,
    float* PURE, float* RNORM,
    const float* l1, const float* l2,
    const float* Wl1, const float* bl1, const float* Wl2, const float* bl2,
    float* LANGB,
    const float* mr, const float* mi, float* VMEAS, short* VMEASB)
{
  __shared__ float xs[600];
  __shared__ float xs2a[300];
  __shared__ float red[4];
  int b = blockIdx.x, tid = threadIdx.x;

  if (b < 384){
    int l = b / 192, bb = b - l*192;
    const float* in; short* out; int K, N, boff;
    if (bb < 48)      { in = Wqkv; out = WqkvT; K = 128; N = 384; boff = bb; }
    else if (bb < 64) { in = Wo;   out = WoT;   K = 128; N = 128; boff = bb - 48; }
    else if (bb < 128){ in = W1;   out = W1T;   K = 128; N = 512; boff = bb - 64; }
    else              { in = W2;   out = W2T;   K = 512; N = 128; boff = bb - 128; }
    int base = l * K * N;
    int i0 = boff * 1024;
    #pragma unroll
    for (int t = 0; t < 8; t++){
      int i = i0 + t*128 + tid;
      if (i < K*N){
        int nn = i / K, kk = i - nn*K;
        out[base + i] = f2bs(in[base + kk*N + nn]);
      }
    }
    return;
  }
  if (b < 1152){
    int idx = b - 384;
    int bt = idx & 255, m = idx >> 8;
    if (m == 0)      modality<600>(xt, Wpt, bpt, pht, PURE, RNORM, 0, bt, xs, red);
    else if (m == 1) modality<342>(xv, Wpv, bpv, phv, PURE, RNORM, 1, bt, xs, red);
    else             modality<300>(xa, Wpa, bpa, pha, PURE, RNORM, 2, bt, xs, red);
    return;
  }
  if (b >= 1153){
    // ---- meas_norm path: one k per block ----
    int k = b - 1153;
    float a = mr[k*128 + tid], bb2 = mi[k*128 + tid];
    float ws = wred_sum(a*a + bb2*bb2);
    int wid = tid >> 6, lane = tid & 63;
    if (lane == 0) red[wid] = ws;
    __syncthreads();
    float inv = 1.f / fmaxf(sqrtf(red[0] + red[1]), 1e-12f);
    float vr = a * inv, vi = bb2 * inv;
    int i = k*128 + tid;
    VMEAS[i]          = vr;
    VMEAS[16384 + i]  = vi;
    VMEASB[i]         = f2bs(vr);
    VMEASB[16384 + i] = f2bs(vi);
    VMEASB[32768 + i] = f2bs(-vi);
    return;
  }
  // ---- lang path (single block, b == 1152) ----
  for (int i = tid; i < 300; i += 128){ xs[i] = l1[i]; xs2a[i] = l2[i]; }
  __syncthreads();
  float p10=0,p11=0,p12=0,p13=0, p20=0,p21=0,p22=0,p23=0;
  for (int k = 0; k < 300; k += 4){
    p10 = fmaf(xs[k],    Wl1[(k  )*128+tid], p10);
    p11 = fmaf(xs[k+1],  Wl1[(k+1)*128+tid], p11);
    p12 = fmaf(xs[k+2],  Wl1[(k+2)*128+tid], p12);
    p13 = fmaf(xs[k+3],  Wl1[(k+3)*128+tid], p13);
    p20 = fmaf(xs2a[k],  Wl2[(k  )*128+tid], p20);
    p21 = fmaf(xs2a[k+1],Wl2[(k+1)*128+tid], p21);
    p22 = fmaf(xs2a[k+2],Wl2[(k+2)*128+tid], p22);
    p23 = fmaf(xs2a[k+3],Wl2[(k+3)*128+tid], p23);
  }
  float a1 = bl1[tid] + ((p10+p11)+(p12+p13));
  float a2 = bl2[tid] + ((p20+p21)+(p22+p23));
  a1 = fmaxf(a1, 0.f); a2 = fmaxf(a2, 0.f);
  int wid = tid >> 6, lane = tid & 63;
  float s1 = wred_sum(a1*a1), s2 = wred_sum(a2*a2);
  if (lane == 0){ red[wid] = s1; red[2+wid] = s2; }
  __syncthreads();
  float n1 = sqrtf(red[0] + red[1]);
  float n2 = sqrtf(red[2] + red[3]);
  float lamp1 = a1 / fmaxf(n1, 1e-12f);
  float lamp2 = a2 / fmaxf(n2, 1e-12f);
  float ph = pht[tid];
  float c = cosf(ph), s = sinf(ph);
  const float s2c = 0.70710678118654752f;
  float h1r = (lamp1*c + lamp1*s)*s2c, h1i = (lamp1*c - lamp1*s)*s2c;
  float h2r = (lamp2*c + lamp2*s)*s2c, h2i = (lamp2*c - lamp2*s)*s2c;
  float er = h1r*h2r - h1i*h2i;
  float ei = h1r*h2i + h1i*h2r;
  __syncthreads();
  float se = wred_sum(er*er + ei*ei);
  if (lane == 0) red[wid] = se;
  __syncthreads();
  float en = fmaxf(sqrtf(red[0] + red[1]), 1e-12f);
  LANGB[tid]       = er / en;
  LANGB[128 + tid] = ei / en;
  if (tid == 0) LANGB[256] = n1;
}

// ---------------------------------------------------------------------------
// Kernel 3: weighted sum of rank-1 density matrices -> Xb (bf16). grid 512.
// ---------------------------------------------------------------------------
__global__ __launch_bounds__(256) void rho_kernel(const float* PURE, const float* RNORM,
                                                  const float* LANGB, short* Xb)
{
  __shared__ float rv[4][128], iv[4][128], wsm[4];
  int bt = blockIdx.x >> 1, half = blockIdx.x & 1;
  int tid = threadIdx.x;
  for (int i = tid; i < 1024; i += 256){
    int d = i & 127;
    if (i < 768){ int m = i >> 7; float v = PURE[bt*768 + i];
                  if (m < 3) rv[m][d] = v; else iv[m-3][d] = v; }
    else if (i < 896) rv[3][d] = LANGB[d];
    else              iv[3][d] = LANGB[128 + d];
  }
  if (tid == 0){
    float n0 = RNORM[bt*4+0], n1 = RNORM[bt*4+1], n2 = RNORM[bt*4+2], n3 = LANGB[256];
    float mx = fmaxf(fmaxf(n0, n1), fmaxf(n2, n3));
    float e0 = __expf(n0-mx), e1 = __expf(n1-mx), e2 = __expf(n2-mx), e3 = __expf(n3-mx);
    float inv = 1.f / (e0+e1+e2+e3);
    wsm[0]=e0*inv; wsm[1]=e1*inv; wsm[2]=e2*inv; wsm[3]=e3*inv;
  }
  __syncthreads();
  float w0 = wsm[0], w1 = wsm[1], w2 = wsm[2], w3 = wsm[3];
  int lo = half*8192, hi = lo + 8192;
  for (int idx = lo + tid; idx < hi; idx += 256){
    int d = idx >> 7, e = idx & 127;
    float rr = 0.f, ri = 0.f;
    {
      float rd=rv[0][d], re=rv[0][e], id=iv[0][d], ie=iv[0][e];
      rr = fmaf(w0, rd*re + id*ie, rr); ri = fmaf(w0, id*re - rd*ie, ri);
    }{
      float rd=rv[1][d], re=rv[1][e], id=iv[1][d], ie=iv[1][e];
      rr = fmaf(w1, rd*re + id*ie, rr); ri = fmaf(w1, id*re - rd*ie, ri);
    }{
      float rd=rv[2][d], re=rv[2][e], id=iv[2][d], ie=iv[2][e];
      rr = fmaf(w2, rd*re + id*ie, rr); ri = fmaf(w2, id*re - rd*ie, ri);
    }{
      float rd=rv[3][d], re=rv[3][e], id=iv[3][d], ie=iv[3][e];
      rr = fmaf(w3, rd*re + id*ie, rr); ri = fmaf(w3, id*re - rd*ie, ri);
    }
    Xb[(size_t)bt*16384 + idx]        = f2bs(rr);
    Xb[(size_t)(256+bt)*16384 + idx]  = f2bs(ri);
  }
}

// ---------------------------------------------------------------------------
// Kernel 4a: fused MHA per (sequence n, head h) via MFMA. grid (512,4), block 256.
// ---------------------------------------------------------------------------
__global__ __launch_bounds__(256) void attn_kernel(const short* __restrict__ Xb,
    const short* __restrict__ WqkvT, const float* __restrict__ bqkv,
    bf16* __restrict__ ATTO)
{
  __shared__ __align__(16) char lds_raw[43520];
  short* Vt = (short*)(lds_raw);           // [32][136]
  short* Qs = (short*)(lds_raw + 8704);    // [128][40]
  short* Ks = (short*)(lds_raw + 18944);   // [128][40]
  short* Ps = (short*)(lds_raw + 8704);    // [128][136] overlays Qs/Ks

  const int n = blockIdx.x, h = blockIdx.y;
  const int tid = threadIdx.x;
  const int wid = tid >> 6, lane = tid & 63;
  const int l15 = lane & 15, quad = lane >> 4;
  const short* xn = Xb + (size_t)n*16384;

  f32x4 acc[2][6];
  #pragma unroll
  for (int mi = 0; mi < 2; mi++)
    #pragma unroll
    for (int nt = 0; nt < 6; nt++){
      f32x4 z = {0.f, 0.f, 0.f, 0.f}; acc[mi][nt] = z;
    }

  #pragma unroll
  for (int ks = 0; ks < 4; ks++){
    short8 afr[2];
    #pragma unroll
    for (int mi = 0; mi < 2; mi++){
      int row = (wid*2 + mi)*16 + l15;
      afr[mi] = *(const short8*)(xn + row*128 + ks*32 + quad*8);
    }
    #pragma unroll
    for (int nt = 0; nt < 6; nt++){
      int col = (nt >> 1)*128 + h*32 + (nt & 1)*16 + l15;
      short8 bfr = *(const short8*)(WqkvT + (size_t)col*128 + ks*32 + quad*8);
      #pragma unroll
      for (int mi = 0; mi < 2; mi++)
        acc[mi][nt] = __builtin_amdgcn_mfma_f32_16x16x32_bf16(afr[mi], bfr, acc[mi][nt], 0, 0, 0);
    }
  }
  #pragma unroll
  for (int nt = 0; nt < 6; nt++){
    int sec = nt >> 1;
    int cl = (nt & 1)*16 + l15;
    float bias = bqkv[sec*128 + h*32 + cl];
    #pragma unroll
    for (int mi = 0; mi < 2; mi++){
      int rowb = (wid*2 + mi)*16 + quad*4;
      #pragma unroll
      for (int r = 0; r < 4; r++){
        float v = acc[mi][nt][r] + bias;
        int row = rowb + r;
        if (sec == 0)      Qs[row*40 + cl] = f2bs(v * 0.17677669529663687f);
        else if (sec == 1) Ks[row*40 + cl] = f2bs(v);
        else               Vt[cl*136 + row] = f2bs(v);
      }
    }
  }
  __syncthreads();

  f32x4 s[2][8];
  {
    short8 qf[2];
    #pragma unroll
    for (int mi = 0; mi < 2; mi++){
      int row = (wid*2 + mi)*16 + l15;
      qf[mi] = *(const short8*)(Qs + row*40 + quad*8);
    }
    #pragma unroll
    for (int nt = 0; nt < 8; nt++){
      int kr = nt*16 + l15;
      short8 kf = *(const short8*)(Ks + kr*40 + quad*8);
      #pragma unroll
      for (int mi = 0; mi < 2; mi++){
        f32x4 z = {0.f, 0.f, 0.f, 0.f};
        s[mi][nt] = __builtin_amdgcn_mfma_f32_16x16x32_bf16(qf[mi], kf, z, 0, 0, 0);
      }
    }
  }

  #pragma unroll
  for (int mi = 0; mi < 2; mi++){
    #pragma unroll
    for (int r = 0; r < 4; r++){
      float m = -1e30f;
      #pragma unroll
      for (int nt = 0; nt < 8; nt++) m = fmaxf(m, s[mi][nt][r]);
      #pragma unroll
      for (int o = 1; o < 16; o <<= 1) m = fmaxf(m, __shfl_xor(m, o, 64));
      float sum = 0.f;
      #pragma unroll
      for (int nt = 0; nt < 8; nt++){
        float p = __expf(s[mi][nt][r] - m);
        s[mi][nt][r] = p; sum += p;
      }
      #pragma unroll
      for (int o = 1; o < 16; o <<= 1) sum += __shfl_xor(sum, o, 64);
      float inv = 1.f / sum;
      #pragma unroll
      for (int nt = 0; nt < 8; nt++) s[mi][nt][r] *= inv;
    }
  }
  __syncthreads();

  #pragma unroll
  for (int mi = 0; mi < 2; mi++){
    int rowb = (wid*2 + mi)*16 + quad*4;
    #pragma unroll
    for (int nt = 0; nt < 8; nt++){
      int col = nt*16 + l15;
      #pragma unroll
      for (int r = 0; r < 4; r++)
        Ps[(rowb + r)*136 + col] = f2bs(s[mi][nt][r]);
    }
  }
  __syncthreads();

  f32x4 o_[2][2];
  #pragma unroll
  for (int mi = 0; mi < 2; mi++)
    #pragma unroll
    for (int n2 = 0; n2 < 2; n2++){
      f32x4 z = {0.f, 0.f, 0.f, 0.f}; o_[mi][n2] = z;
    }
  #pragma unroll
  for (int ks = 0; ks < 4; ks++){
    short8 pf[2];
    #pragma unroll
    for (int mi = 0; mi < 2; mi++){
      int row = (wid*2 + mi)*16 + l15;
      pf[mi] = *(const short8*)(Ps + row*136 + ks*32 + quad*8);
    }
    #pragma unroll
    for (int n2 = 0; n2 < 2; n2++){
      short8 vf = *(const short8*)(Vt + (n2*16 + l15)*136 + ks*32 + quad*8);
      #pragma unroll
      for (int mi = 0; mi < 2; mi++)
        o_[mi][n2] = __builtin_amdgcn_mfma_f32_16x16x32_bf16(pf[mi], vf, o_[mi][n2], 0, 0, 0);
    }
  }
  bf16* on = ATTO + (size_t)n*16384;
  #pragma unroll
  for (int mi = 0; mi < 2; mi++){
    int rowb = (wid*2 + mi)*16 + quad*4;
    #pragma unroll
    for (int n2 = 0; n2 < 2; n2++){
      int col = h*32 + n2*16 + l15;
      #pragma unroll
      for (int r = 0; r < 4; r++)
        on[(rowb + r)*128 + col] = __float2bfloat16(o_[mi][n2][r]);
    }
  }
}

// ---------------------------------------------------------------------------
// Kernel 4bc FUSED, barrier-free, FF chunked to 32 cols (round-15 version,
// measured best 81 us): grid 512, block 256, LDS 44 KB -> 3 blocks/CU.
// ---------------------------------------------------------------------------
__global__ __launch_bounds__(256, 3) void proj_ffn_kernel(const bf16* __restrict__ SRC,
    short* __restrict__ Xb, const short* __restrict__ WoT,
    const float* __restrict__ bo, const float* __restrict__ g1v,
    const float* __restrict__ bb1,
    const short* __restrict__ W1T, const float* __restrict__ bf1,
    const short* __restrict__ W2T, const float* __restrict__ bf2,
    const float* __restrict__ g2v, const float* __restrict__ bb2)
{
  __shared__ __align__(16) short Xs[128*136];
  __shared__ __align__(16) short Hs[128*40];
  const int n = blockIdx.x, tid = threadIdx.x;
  const int wid = tid >> 6, lane = tid & 63;
  const int l15 = lane & 15, quad = lane >> 4;
  const short* an = (const short*)SRC + (size_t)n*16384;
  short* xn = Xb + (size_t)n*16384;

  f32x4 Y[2][8];
  #pragma unroll
  for (int mi = 0; mi < 2; mi++)
    #pragma unroll
    for (int nt = 0; nt < 8; nt++){ f32x4 z = {0.f,0.f,0.f,0.f}; Y[mi][nt] = z; }

  #pragma unroll
  for (int ks = 0; ks < 4; ks++){
    short8 af[2];
    #pragma unroll
    for (int mi = 0; mi < 2; mi++){
      int row = (wid*2 + mi)*16 + l15;
      af[mi] = *(const short8*)(an + row*128 + ks*32 + quad*8);
    }
    #pragma unroll
    for (int nt = 0; nt < 8; nt++){
      int coln = nt*16 + l15;
      short8 bh = *(const short8*)(WoT + coln*128 + ks*32 + quad*8);
      #pragma unroll
      for (int mi = 0; mi < 2; mi++)
        Y[mi][nt] = __builtin_amdgcn_mfma_f32_16x16x32_bf16(af[mi], bh, Y[mi][nt], 0, 0, 0);
    }
  }

  {
    float bov[8], gv[8], bbv[8];
    #pragma unroll
    for (int nt = 0; nt < 8; nt++){
      int col = nt*16 + l15;
      bov[nt] = bo[col]; gv[nt] = g1v[col]; bbv[nt] = bb1[col];
    }
    #pragma unroll
    for (int mi = 0; mi < 2; mi++){
      #pragma unroll
      for (int r = 0; r < 4; r++){
        int row = (wid*2 + mi)*16 + quad*4 + r;
        float yv[8]; float S = 0.f, Q = 0.f;
        #pragma unroll
        for (int nt = 0; nt < 8; nt++){
          int col = nt*16 + l15;
          float y = Y[mi][nt][r] + bov[nt] + bs2f(xn[row*128 + col]);
          yv[nt] = y; S += y; Q += y*y;
        }
        #pragma unroll
        for (int o = 1; o < 16; o <<= 1){ S += __shfl_xor(S, o, 64); Q += __shfl_xor(Q, o, 64); }
        float m = S * (1.f/128.f);
        float var = Q * (1.f/128.f) - m*m;
        float inv = rsqrtf(var + 1e-5f);
        #pragma unroll
        for (int nt = 0; nt < 8; nt++){
          int col = nt*16 + l15;
          Xs[row*136 + col] = f2bs((yv[nt] - m) * inv * gv[nt] + bbv[nt]);
        }
      }
    }
  }

  short8 af2[2][4];
  #pragma unroll
  for (int mi = 0; mi < 2; mi++){
    int row = (wid*2 + mi)*16 + l15;
    #pragma unroll
    for (int ks = 0; ks < 4; ks++)
      af2[mi][ks] = *(const short8*)(Xs + row*136 + ks*32 + quad*8);
  }

  f32x4 Y2[2][8];
  #pragma unroll
  for (int mi = 0; mi < 2; mi++)
    #pragma unroll
    for (int nt = 0; nt < 8; nt++){ f32x4 z = {0.f,0.f,0.f,0.f}; Y2[mi][nt] = z; }

  for (int c = 0; c < 16; c++){
    f32x4 Hc[2][2];
    #pragma unroll
    for (int mi = 0; mi < 2; mi++)
      #pragma unroll
      for (int nt = 0; nt < 2; nt++){ f32x4 z = {0.f,0.f,0.f,0.f}; Hc[mi][nt] = z; }
    #pragma unroll
    for (int ks = 0; ks < 4; ks++){
      #pragma unroll
      for (int nt = 0; nt < 2; nt++){
        int colg = c*32 + nt*16 + l15;
        short8 bh = *(const short8*)(W1T + colg*128 + ks*32 + quad*8);
        #pragma unroll
        for (int mi = 0; mi < 2; mi++)
          Hc[mi][nt] = __builtin_amdgcn_mfma_f32_16x16x32_bf16(af2[mi][ks], bh, Hc[mi][nt], 0, 0, 0);
      }
    }
    #pragma unroll
    for (int nt = 0; nt < 2; nt++){
      int col = nt*16 + l15;
      float b1v = bf1[c*32 + col];
      #pragma unroll
      for (int mi = 0; mi < 2; mi++){
        int rowb = (wid*2 + mi)*16 + quad*4;
        #pragma unroll
        for (int r = 0; r < 4; r++)
          Hs[(rowb + r)*40 + col] = f2bs(fmaxf(Hc[mi][nt][r] + b1v, 0.f));
      }
    }
    short8 ph[2];
    #pragma unroll
    for (int mi = 0; mi < 2; mi++){
      int row = (wid*2 + mi)*16 + l15;
      ph[mi] = *(const short8*)(Hs + row*40 + quad*8);
    }
    #pragma unroll
    for (int nt = 0; nt < 8; nt++){
      int coln = nt*16 + l15;
      short8 bh = *(const short8*)(W2T + coln*512 + c*32 + quad*8);
      #pragma unroll
      for (int mi = 0; mi < 2; mi++)
        Y2[mi][nt] = __builtin_amdgcn_mfma_f32_16x16x32_bf16(ph[mi], bh, Y2[mi][nt], 0, 0, 0);
    }
  }

  {
    float b2v[8], gv[8], bbv[8];
    #pragma unroll
    for (int nt = 0; nt < 8; nt++){
      int col = nt*16 + l15;
      b2v[nt] = bf2[col]; gv[nt] = g2v[col]; bbv[nt] = bb2[col];
    }
    #pragma unroll
    for (int mi = 0; mi < 2; mi++){
      #pragma unroll
      for (int r = 0; r < 4; r++){
        int row = (wid*2 + mi)*16 + quad*4 + r;
        float yv[8]; float S = 0.f, Q = 0.f;
        #pragma unroll
        for (int nt = 0; nt < 8; nt++){
          int col = nt*16 + l15;
          float y = Y2[mi][nt][r] + b2v[nt] + bs2f(Xs[row*136 + col]);
          yv[nt] = y; S += y; Q += y*y;
        }
        #pragma unroll
        for (int o = 1; o < 16; o <<= 1){ S += __shfl_xor(S, o, 64); Q += __shfl_xor(Q, o, 64); }
        float m = S * (1.f/128.f);
        float var = Q * (1.f/128.f) - m*m;
        float inv = rsqrtf(var + 1e-5f);
        #pragma unroll
        for (int nt = 0; nt < 8; nt++){
          int col = nt*16 + l15;
          xn[row*128 + col] = f2bs((yv[nt] - m) * inv * gv[nt] + bbv[nt]);
        }
      }
    }
  }
}

// ---------------------------------------------------------------------------
// Kernel 5b: probs[k] = Re(v_k^dag rho v_k) via MFMA.
// ---------------------------------------------------------------------------
__global__ __launch_bounds__(256) void probs_kernel(const short* __restrict__ Xb,
    const float* __restrict__ VMEAS, const short* __restrict__ VMEASB,
    float* __restrict__ PROBS)
{
  __shared__ float sp[128];
  const int bt = blockIdx.x, z = blockIdx.y, tid = threadIdx.x;
  const int wid = tid >> 6, lane = tid & 63;
  const int l15 = lane & 15, quad = lane >> 4;
  const short* R = Xb + (size_t)bt*16384;
  const short* I = Xb + (size_t)(256+bt)*16384;
  const short* vrB  = VMEASB;
  const short* viB  = VMEASB + 16384;
  const short* nviB = VMEASB + 32768;

  if (tid < 128) sp[tid] = 0.f;
  __syncthreads();

  const int drow = z*64 + wid*16 + l15;
  short8 aR[4], aI[4];
  #pragma unroll
  for (int ks = 0; ks < 4; ks++){
    aR[ks] = *(const short8*)(R + drow*128 + ks*32 + quad*8);
    aI[ks] = *(const short8*)(I + drow*128 + ks*32 + quad*8);
  }

  float p[8];
  #pragma unroll
  for (int nt = 0; nt < 8; nt++) p[nt] = 0.f;
  const int db = z*64 + wid*16 + quad*4;

  {
    f32x4 Ar[8];
    #pragma unroll
    for (int nt = 0; nt < 8; nt++){ f32x4 zz = {0.f,0.f,0.f,0.f}; Ar[nt] = zz; }
    #pragma unroll
    for (int ks = 0; ks < 4; ks++){
      #pragma unroll
      for (int nt = 0; nt < 8; nt++){
        int coln = nt*16 + l15;
        short8 b1 = *(const short8*)(vrB  + coln*128 + ks*32 + quad*8);
        short8 b2 = *(const short8*)(nviB + coln*128 + ks*32 + quad*8);
        Ar[nt] = __builtin_amdgcn_mfma_f32_16x16x32_bf16(aR[ks], b1, Ar[nt], 0, 0, 0);
        Ar[nt] = __builtin_amdgcn_mfma_f32_16x16x32_bf16(aI[ks], b2, Ar[nt], 0, 0, 0);
      }
    }
    #pragma unroll
    for (int nt = 0; nt < 8; nt++){
      int k = nt*16 + l15;
      #pragma unroll
      for (int r = 0; r < 4; r++)
        p[nt] = fmaf(VMEAS[k*128 + db + r], Ar[nt][r], p[nt]);
    }
  }
  {
    f32x4 Ai[8];
    #pragma unroll
    for (int nt = 0; nt < 8; nt++){ f32x4 zz = {0.f,0.f,0.f,0.f}; Ai[nt] = zz; }
    #pragma unroll
    for (int ks = 0; ks < 4; ks++){
      #pragma unroll
      for (int nt = 0; nt < 8; nt++){
        int coln = nt*16 + l15;
        short8 b1 = *(const short8*)(viB + coln*128 + ks*32 + quad*8);
        short8 b2 = *(const short8*)(vrB + coln*128 + ks*32 + quad*8);
        Ai[nt] = __builtin_amdgcn_mfma_f32_16x16x32_bf16(aR[ks], b1, Ai[nt], 0, 0, 0);
        Ai[nt] = __builtin_amdgcn_mfma_f32_16x16x32_bf16(aI[ks], b2, Ai[nt], 0, 0, 0);
      }
    }
    #pragma unroll
    for (int nt = 0; nt < 8; nt++){
      int k = nt*16 + l15;
      #pragma unroll
      for (int r = 0; r < 4; r++)
        p[nt] = fmaf(VMEAS[16384 + k*128 + db + r], Ai[nt][r], p[nt]);
    }
  }

  #pragma unroll
  for (int nt = 0; nt < 8; nt++){
    float v = p[nt];
    v += __shfl_xor(v, 16, 64);
    v += __shfl_xor(v, 32, 64);
    if (quad == 0) atomicAdd(&sp[nt*16 + l15], v);
  }
  __syncthreads();
  if (tid < 128) PROBS[(size_t)(z*256 + bt)*128 + tid] = sp[tid];
}

// ---------------------------------------------------------------------------
// Kernel 6: classifier head + log_softmax. grid 256, block 64.
// ---------------------------------------------------------------------------
__global__ void head_kernel(const float* PROBS, const float* W1, const float* b1,
                            const float* W2, const float* b2, float* out)
{
  __shared__ float h[64];
  __shared__ float lg[7];
  __shared__ float mred[2];
  int bt = blockIdx.x, tid = threadIdx.x;
  float a0 = b1[tid], a1 = 0.f, a2 = 0.f, a3 = 0.f;
  for (int d = 0; d < 128; d += 4){
    float p0 = PROBS[bt*128 + d  ] + PROBS[(256+bt)*128 + d  ];
    float p1 = PROBS[bt*128 + d+1] + PROBS[(256+bt)*128 + d+1];
    float p2 = PROBS[bt*128 + d+2] + PROBS[(256+bt)*128 + d+2];
    float p3 = PROBS[bt*128 + d+3] + PROBS[(256+bt)*128 + d+3];
    a0 = fmaf(p0, W1[(d  )*64 + tid], a0);
    a1 = fmaf(p1, W1[(d+1)*64 + tid], a1);
    a2 = fmaf(p2, W1[(d+2)*64 + tid], a2);
    a3 = fmaf(p3, W1[(d+3)*64 + tid], a3);
  }
  h[tid] = fmaxf((a0 + a1) + (a2 + a3), 0.f);
  __syncthreads();
  if (tid < 7){
    float a = b2[tid];
    for (int j = 0; j < 64; j++) a = fmaf(h[j], W2[j*7 + tid], a);
    lg[tid] = a;
  }
  __syncthreads();
  if (tid == 0){
    float M = -1e30f;
    for (int c = 0; c < 7; c++) M = fmaxf(M, lg[c]);
    float S = 0.f;
    for (int c = 0; c < 7; c++) S += __expf(lg[c] - M);
    mred[0] = M; mred[1] = logf(S);
  }
  __syncthreads();
  if (tid < 7) out[bt*7 + tid] = lg[tid] - mred[0] - mred[1];
}

// ---------------------------------------------------------------------------
extern "C" void kernel_launch(void* const* d_in, const int* in_sizes, int n_in,
                              void* d_out, int out_size, void* d_ws, size_t ws_size,
                              hipStream_t stream)
{
  (void)in_sizes; (void)n_in; (void)out_size; (void)ws_size;
  const float* xt   = (const float*)d_in[0];
  const float* xv   = (const float*)d_in[1];
  const float* xa   = (const float*)d_in[2];
  const float* Wpt  = (const float*)d_in[3];
  const float* bpt  = (const float*)d_in[4];
  const float* Wpv  = (const float*)d_in[5];
  const float* bpv  = (const float*)d_in[6];
  const float* Wpa  = (const float*)d_in[7];
  const float* bpa  = (const float*)d_in[8];
  const float* l1   = (const float*)d_in[9];
  const float* l2   = (const float*)d_in[10];
  const float* Wl1  = (const float*)d_in[11];
  const float* bl1  = (const float*)d_in[12];
  const float* Wl2  = (const float*)d_in[13];
  const float* bl2  = (const float*)d_in[14];
  const float* pht  = (const float*)d_in[15];
  const float* phv  = (const float*)d_in[16];
  const float* pha  = (const float*)d_in[17];
  const float* Wqkv = (const float*)d_in[18];
  const float* bqkv = (const float*)d_in[19];
  const float* Wo   = (const float*)d_in[20];
  const float* bo   = (const float*)d_in[21];
  const float* g1   = (const float*)d_in[22];
  const float* b1   = (const float*)d_in[23];
  const float* W1   = (const float*)d_in[24];
  const float* bf1  = (const float*)d_in[25];
  const float* W2   = (const float*)d_in[26];
  const float* bf2  = (const float*)d_in[27];
  const float* g2   = (const float*)d_in[28];
  const float* b2   = (const float*)d_in[29];
  const float* mr   = (const float*)d_in[30];
  const float* mi   = (const float*)d_in[31];
  const float* fcW1 = (const float*)d_in[32];
  const float* fcb1 = (const float*)d_in[33];
  const float* fcW2 = (const float*)d_in[34];
  const float* fcb2 = (const float*)d_in[35];
  float* out = (float*)d_out;

  // workspace layout (bytes) -- total ~34 MiB. All transposed weights = 2 layers.
  char* wsb = (char*)d_ws;
  short* Xb     = (short*)(wsb);                        // 16777216 B (bf16 X stream)
  bf16*  ATTO   = (bf16*) (wsb + 16777216);             // 16777216 B
  float* PURE   = (float*)(wsb + 33554432);             // 786432 B
  float* RNORM  = (float*)(wsb + 34340864);             // 4096 B
  float* LANGB  = (float*)(wsb + 34344960);             // 2048 B
  float* VMEAS  = (float*)(wsb + 34347008);             // 131072 B
  float* PROBS  = (float*)(wsb + 34478080);             // 262144 B
  short* WqkvT  = (short*)(wsb + 34740224);             // 196608 B
  short* WoT    = (short*)(wsb + 34936832);             // 65536 B
  short* W1T    = (short*)(wsb + 35002368);             // 262144 B
  short* W2T    = (short*)(wsb + 35264512);             // 262144 B
  short* VMEASB = (short*)(wsb + 35526656);             // 98304 B

  prep_kernel<<<1281, 128, 0, stream>>>(Wqkv, Wo, W1, W2, WqkvT, WoT, W1T, W2T,
                                        xt, xv, xa, Wpt, bpt, Wpv, bpv, Wpa, bpa,
                                        pht, phv, pha, PURE, RNORM,
                                        l1, l2, Wl1, bl1, Wl2, bl2, LANGB,
                                        mr, mi, VMEAS, VMEASB);

  rho_kernel<<<512, 256, 0, stream>>>(PURE, RNORM, LANGB, Xb);

  for (int l = 0; l < 2; l++){
    attn_kernel<<<dim3(512, 4), 256, 0, stream>>>(Xb, WqkvT + (size_t)l*49152,
                                                  bqkv + (size_t)l*384, ATTO);
    proj_ffn_kernel<<<512, 256, 0, stream>>>(ATTO, Xb,
                                             WoT + (size_t)l*16384,
                                             bo + (size_t)l*128, g1 + (size_t)l*128,
                                             b1 + (size_t)l*128,
                                             W1T + (size_t)l*65536, bf1 + (size_t)l*512,
                                             W2T + (size_t)l*65536, bf2 + (size_t)l*128,
                                             g2 + (size_t)l*128, b2 + (size_t)l*128);
  }

  probs_kernel<<<dim3(256, 2), 256, 0, stream>>>(Xb, VMEAS, VMEASB, PROBS);
  head_kernel<<<256, 64, 0, stream>>>(PROBS, fcW1, fcb1, fcW2, fcb2, out);
}